// Round 1
// baseline (1947.834 us; speedup 1.0000x reference)
//
#include <hip/hip_runtime.h>
#include <math.h>

#define Bb 8
#define Ss 1024
#define Ee 768
#define Hh 12
#define Dd 64
#define Mm (Bb*Ss)   // 8192 rows

// ---------------- block-wide sum over 256 threads ----------------
__device__ __forceinline__ float block_sum_256(float v, float* red) {
    #pragma unroll
    for (int off = 32; off > 0; off >>= 1) v += __shfl_down(v, off, 64);
    __syncthreads();                       // protect red reuse across calls
    if ((threadIdx.x & 63) == 0) red[threadIdx.x >> 6] = v;
    __syncthreads();
    return red[0] + red[1] + red[2] + red[3];
}

// ---------------- per-row L2 norm (raw input rows) ----------------
__global__ __launch_bounds__(256) void row_norm_kernel(const float* __restrict__ A,
                                                       float* __restrict__ out) {
    __shared__ float red[4];
    size_t row = blockIdx.x;
    const float* a = A + row * Ee;
    float s = 0.f;
    #pragma unroll
    for (int l = 0; l < 3; ++l) { float x = a[threadIdx.x + l*256]; s += x*x; }
    float tot = block_sum_256(s, red);
    if (threadIdx.x == 0) out[row] = fmaxf(sqrtf(tot), 1e-15f);
}

// ---------------- C[M,768] = A[M,768] @ W[768,768]^T (fp32, NT) ----------------
// 128x64 tile, BK=32, 256 threads, 8x4 micro-tile.
__global__ __launch_bounds__(256) void gemm_nt_kernel(const float* __restrict__ A,
                                                      const float* __restrict__ W,
                                                      float* __restrict__ C) {
    __shared__ float As[32][132];   // [k][m], padded: conflict-light
    __shared__ float Bs[32][68];    // [k][n]
    const int tid = threadIdx.x;
    const int tx = tid & 15, ty = tid >> 4;
    const int mBase = blockIdx.x * 128, nBase = blockIdx.y * 64;
    float acc[8][4];
    #pragma unroll
    for (int i = 0; i < 8; ++i)
        #pragma unroll
        for (int j = 0; j < 4; ++j) acc[i][j] = 0.f;

    for (int k0 = 0; k0 < Ee; k0 += 32) {
        #pragma unroll
        for (int l = 0; l < 4; ++l) {           // A tile: 128x32
            int f4 = tid + l*256;
            int row = f4 >> 3, kq = (f4 & 7) << 2;
            float4 v = *reinterpret_cast<const float4*>(&A[(size_t)(mBase+row)*Ee + k0 + kq]);
            As[kq+0][row] = v.x; As[kq+1][row] = v.y; As[kq+2][row] = v.z; As[kq+3][row] = v.w;
        }
        #pragma unroll
        for (int l = 0; l < 2; ++l) {           // W tile: 64x32
            int f4 = tid + l*256;
            int row = f4 >> 3, kq = (f4 & 7) << 2;
            float4 v = *reinterpret_cast<const float4*>(&W[(size_t)(nBase+row)*Ee + k0 + kq]);
            Bs[kq+0][row] = v.x; Bs[kq+1][row] = v.y; Bs[kq+2][row] = v.z; Bs[kq+3][row] = v.w;
        }
        __syncthreads();
        #pragma unroll
        for (int kk = 0; kk < 32; ++kk) {
            float4 a0 = *reinterpret_cast<const float4*>(&As[kk][ty*8]);
            float4 a1 = *reinterpret_cast<const float4*>(&As[kk][ty*8+4]);
            float4 b0 = *reinterpret_cast<const float4*>(&Bs[kk][tx*4]);
            float am[8] = {a0.x,a0.y,a0.z,a0.w,a1.x,a1.y,a1.z,a1.w};
            float bn[4] = {b0.x,b0.y,b0.z,b0.w};
            #pragma unroll
            for (int i = 0; i < 8; ++i)
                #pragma unroll
                for (int j = 0; j < 4; ++j) acc[i][j] = fmaf(am[i], bn[j], acc[i][j]);
        }
        __syncthreads();
    }
    #pragma unroll
    for (int i = 0; i < 8; ++i) {
        float4 v = make_float4(acc[i][0], acc[i][1], acc[i][2], acc[i][3]);
        *reinterpret_cast<float4*>(&C[(size_t)(mBase + ty*8 + i)*Ee + nBase + tx*4]) = v;
    }
}

// ---------------- per-row mobius scale + mobius_add(., bias) ----------------
// src may equal dst (in-place): each block touches only its own row.
__global__ __launch_bounds__(256) void mobius_fix_kernel(const float* src, float* dst,
                                                         const float* __restrict__ xn_buf,
                                                         const float* __restrict__ bias) {
    __shared__ float red[4], red2[4];
    size_t row = blockIdx.x;
    const float* m = src + row * Ee;
    float mv[3], bv[3];
    float ss = 0.f;
    #pragma unroll
    for (int l = 0; l < 3; ++l) { mv[l] = m[threadIdx.x + l*256]; ss += mv[l]*mv[l]; }
    float mxn2 = block_sum_256(ss, red);
    float mxn = fmaxf(sqrtf(mxn2), 1e-15f);
    float xn = xn_buf[row];
    float xc = fminf(xn, 1.f - 1e-7f);
    float at = 0.5f * logf((1.f + xc) / (1.f - xc));     // artanh(clipped xn)
    float th = tanhf(mxn / xn * at);
    float scale = th / mxn;
    float m2 = th * th;                                   // |scale*mx|^2
    float mb = 0.f, b2 = 0.f;
    #pragma unroll
    for (int l = 0; l < 3; ++l) {
        bv[l] = bias[threadIdx.x + l*256];
        mv[l] *= scale;
        mb += mv[l]*bv[l];
        b2 += bv[l]*bv[l];
    }
    mb = block_sum_256(mb, red);
    b2 = block_sum_256(b2, red2);
    float ncoef = 1.f + 2.f*mb + b2;
    float bcoef = 1.f - m2;
    float inv = 1.f / (1.f + 2.f*mb + m2*b2 + 1e-15f);
    float* d = dst + row * Ee;
    #pragma unroll
    for (int l = 0; l < 3; ++l)
        d[threadIdx.x + l*256] = (ncoef*mv[l] + bcoef*bv[l]) * inv;
}

// ---------------- hyperbolic attention, 8 q-rows per block ----------------
// out may alias q: block (b,h,qt) reads exactly the q-slice it later writes.
__global__ __launch_bounds__(256) void attn_kernel(const float* q, const float* k,
                                                   const float* v,
                                                   const float* __restrict__ hs,
                                                   float* out) {
    __shared__ float qs[8][68];
    __shared__ float kvs[64][68];
    __shared__ float q2s[8];
    __shared__ float k2s[64];
    __shared__ float sc[8][1024];
    const int tid = threadIdx.x;
    const int qt = blockIdx.x, h = blockIdx.y, b = blockIdx.z;
    const int q0 = qt * 8;
    const size_t rowBase = (size_t)b * Ss;
    const int hoff = h * 64;
    const float CL = 1.f - 1e-5f;

    #pragma unroll
    for (int l = 0; l < 2; ++l) {
        int id = tid + l*256;
        int r = id >> 6, d = id & 63;
        qs[r][d] = fminf(q[(rowBase + q0 + r)*Ee + hoff + d], CL);
    }
    __syncthreads();
    if (tid < 8) {
        float s = 0.f;
        for (int d = 0; d < 64; ++d) { float x = qs[tid][d]; s += x*x; }
        q2s[tid] = s;
    }
    const float inv_s = 1.f / (hs[h] * 8.0f);   // /(head_scaling*sqrt(64))
    const int kj = tid & 63;
    const int qiA = tid >> 6, qiB = qiA + 4;

    // ---- phase 1: all hyperbolic scores into LDS ----
    for (int kt = 0; kt < 16; ++kt) {
        __syncthreads();
        {   // stage clamped K tile + per-row k2
            int r = tid >> 2, d0 = (tid & 3) << 4;
            const float* kp = &k[(rowBase + kt*64 + r)*Ee + hoff + d0];
            float part = 0.f;
            #pragma unroll
            for (int u = 0; u < 4; ++u) {
                float4 vv = *reinterpret_cast<const float4*>(kp + u*4);
                vv.x = fminf(vv.x, CL); vv.y = fminf(vv.y, CL);
                vv.z = fminf(vv.z, CL); vv.w = fminf(vv.w, CL);
                kvs[r][d0+u*4+0] = vv.x; kvs[r][d0+u*4+1] = vv.y;
                kvs[r][d0+u*4+2] = vv.z; kvs[r][d0+u*4+3] = vv.w;
                part += vv.x*vv.x + vv.y*vv.y + vv.z*vv.z + vv.w*vv.w;
            }
            part += __shfl_xor(part, 1);
            part += __shfl_xor(part, 2);
            if ((tid & 3) == 0) k2s[r] = part;
        }
        __syncthreads();
        {
            float dotA = 0.f, dotB = 0.f;
            #pragma unroll
            for (int d4 = 0; d4 < 16; ++d4) {
                float4 kv = *reinterpret_cast<const float4*>(&kvs[kj][d4<<2]);
                float4 qa = *reinterpret_cast<const float4*>(&qs[qiA][d4<<2]);
                float4 qb = *reinterpret_cast<const float4*>(&qs[qiB][d4<<2]);
                dotA += qa.x*kv.x + qa.y*kv.y + qa.z*kv.z + qa.w*kv.w;
                dotB += qb.x*kv.x + qb.y*kv.y + qb.z*kv.z + qb.w*kv.w;
            }
            float k2 = k2s[kj];
            float q2 = q2s[qiA];
            float numer = 2.f*(q2 + k2 - 2.f*dotA);
            float denom = (1.f - q2)*(1.f - k2) + 1e-15f;
            float t = fmaxf(numer/denom, 0.f);
            float dist = log1pf(t + sqrtf(t*(t + 2.f)));   // arccosh(1+t)
            sc[qiA][kt*64 + kj] = -fmaxf(dist, 1e-7f) * inv_s;
            q2 = q2s[qiB];
            numer = 2.f*(q2 + k2 - 2.f*dotB);
            denom = (1.f - q2)*(1.f - k2) + 1e-15f;
            t = fmaxf(numer/denom, 0.f);
            dist = log1pf(t + sqrtf(t*(t + 2.f)));
            sc[qiB][kt*64 + kj] = -fmaxf(dist, 1e-7f) * inv_s;
        }
    }
    __syncthreads();

    // ---- phase 2: softmax per q-row (32 threads per row) ----
    {
        int r = tid >> 5, l2 = tid & 31;
        float mx = -1e30f;
        #pragma unroll
        for (int i = 0; i < 32; ++i) mx = fmaxf(mx, sc[r][l2 + i*32]);
        #pragma unroll
        for (int off = 16; off > 0; off >>= 1) mx = fmaxf(mx, __shfl_xor(mx, off));
        float sum = 0.f;
        #pragma unroll
        for (int i = 0; i < 32; ++i) {
            float e = expf(sc[r][l2 + i*32] - mx);
            sc[r][l2 + i*32] = e;
            sum += e;
        }
        #pragma unroll
        for (int off = 16; off > 0; off >>= 1) sum += __shfl_xor(sum, off);
        float inv = 1.f / sum;
        #pragma unroll
        for (int i = 0; i < 32; ++i) sc[r][l2 + i*32] *= inv;
    }

    // ---- phase 3: PV ----
    float accA = 0.f, accB = 0.f;
    const int d = tid & 63;
    for (int vt = 0; vt < 16; ++vt) {
        __syncthreads();
        {
            int r = tid >> 2, d0 = (tid & 3) << 4;
            const float* vp = &v[(rowBase + vt*64 + r)*Ee + hoff + d0];
            #pragma unroll
            for (int u = 0; u < 4; ++u) {
                float4 vv = *reinterpret_cast<const float4*>(vp + u*4);
                kvs[r][d0+u*4+0] = vv.x; kvs[r][d0+u*4+1] = vv.y;
                kvs[r][d0+u*4+2] = vv.z; kvs[r][d0+u*4+3] = vv.w;
            }
        }
        __syncthreads();
        #pragma unroll
        for (int j = 0; j < 64; ++j) {
            float vv = kvs[j][d];
            accA = fmaf(sc[qiA][vt*64 + j], vv, accA);
            accB = fmaf(sc[qiB][vt*64 + j], vv, accB);
        }
    }
    out[(rowBase + q0 + qiA)*Ee + hoff + d] = accA;
    out[(rowBase + q0 + qiB)*Ee + hoff + d] = accB;
}

extern "C" void kernel_launch(void* const* d_in, const int* in_sizes, int n_in,
                              void* d_out, int out_size, void* d_ws, size_t ws_size,
                              hipStream_t stream) {
    const float* x  = (const float*)d_in[0];
    const float* Wq = (const float*)d_in[1];
    const float* bq = (const float*)d_in[2];
    const float* Wk = (const float*)d_in[3];
    const float* bk = (const float*)d_in[4];
    const float* Wv = (const float*)d_in[5];
    const float* bv = (const float*)d_in[6];
    const float* Wo = (const float*)d_in[7];
    const float* bo = (const float*)d_in[8];
    const float* hs = (const float*)d_in[9];
    float* out = (float*)d_out;

    float* ws   = (float*)d_ws;
    float* xn_x = ws;                                  // 8192
    float* xn_o = ws + 8192;                           // 8192
    float* mq   = ws + 16384;                          // 8192*768
    float* mk   = mq + (size_t)Mm * Ee;                // 8192*768
    float* mv   = mk + (size_t)Mm * Ee;                // 8192*768
    // total 75.6 MB; attn output aliases mq, o-projection aliases mk.

    dim3 gemm_grid(Mm/128, Ee/64);

    row_norm_kernel<<<Mm, 256, 0, stream>>>(x, xn_x);
    gemm_nt_kernel<<<gemm_grid, 256, 0, stream>>>(x, Wq, mq);
    gemm_nt_kernel<<<gemm_grid, 256, 0, stream>>>(x, Wk, mk);
    gemm_nt_kernel<<<gemm_grid, 256, 0, stream>>>(x, Wv, mv);
    mobius_fix_kernel<<<Mm, 256, 0, stream>>>(mq, mq, xn_x, bq);
    mobius_fix_kernel<<<Mm, 256, 0, stream>>>(mk, mk, xn_x, bk);
    mobius_fix_kernel<<<Mm, 256, 0, stream>>>(mv, mv, xn_x, bv);

    attn_kernel<<<dim3(Ss/8, Hh, Bb), 256, 0, stream>>>(mq, mk, mv, hs, mq);

    row_norm_kernel<<<Mm, 256, 0, stream>>>(mq, xn_o);
    gemm_nt_kernel<<<gemm_grid, 256, 0, stream>>>(mq, Wo, mk);
    mobius_fix_kernel<<<Mm, 256, 0, stream>>>(mk, out, xn_o, bo);
}

// Round 2
// 809.944 us; speedup vs baseline: 2.4049x; 2.4049x over previous
//
#include <hip/hip_runtime.h>
#include <math.h>

#define Bb 8
#define Ss 1024
#define Ee 768
#define Hh 12
#define Dd 64
#define Mm (Bb*Ss)   // 8192 rows

typedef short  s16x8 __attribute__((ext_vector_type(8)));   // 8 bf16 (4 VGPRs)
typedef float  f32x4 __attribute__((ext_vector_type(4)));

__device__ __forceinline__ unsigned short bf16_rne(float f) {
    unsigned u = __float_as_uint(f);
    u += 0x7fff + ((u >> 16) & 1);
    return (unsigned short)(u >> 16);
}
__device__ __forceinline__ float bf16f(unsigned short h) {
    return __uint_as_float(((unsigned)h) << 16);
}

// ---------------- block-wide sum over 256 threads ----------------
__device__ __forceinline__ float block_sum_256(float v, float* red) {
    #pragma unroll
    for (int off = 32; off > 0; off >>= 1) v += __shfl_down(v, off, 64);
    __syncthreads();
    if ((threadIdx.x & 63) == 0) red[threadIdx.x >> 6] = v;
    __syncthreads();
    return red[0] + red[1] + red[2] + red[3];
}

// ---------------- per-row L2 norm ----------------
__global__ __launch_bounds__(256) void row_norm_kernel(const float* __restrict__ A,
                                                       float* __restrict__ out) {
    __shared__ float red[4];
    size_t row = blockIdx.x;
    const float* a = A + row * Ee;
    float s = 0.f;
    #pragma unroll
    for (int l = 0; l < 3; ++l) { float x = a[threadIdx.x + l*256]; s += x*x; }
    float tot = block_sum_256(s, red);
    if (threadIdx.x == 0) out[row] = fmaxf(sqrtf(tot), 1e-15f);
}

// ---------------- C[M,768] = A[M,768] @ W[768,768]^T (fp32, NT) ----------------
__global__ __launch_bounds__(256) void gemm_nt_kernel(const float* __restrict__ A,
                                                      const float* __restrict__ W,
                                                      float* __restrict__ C) {
    __shared__ float As[32][132];
    __shared__ float Bs[32][68];
    const int tid = threadIdx.x;
    const int tx = tid & 15, ty = tid >> 4;
    const int mBase = blockIdx.x * 128, nBase = blockIdx.y * 64;
    float acc[8][4];
    #pragma unroll
    for (int i = 0; i < 8; ++i)
        #pragma unroll
        for (int j = 0; j < 4; ++j) acc[i][j] = 0.f;

    for (int k0 = 0; k0 < Ee; k0 += 32) {
        #pragma unroll
        for (int l = 0; l < 4; ++l) {
            int f4 = tid + l*256;
            int row = f4 >> 3, kq = (f4 & 7) << 2;
            float4 v = *reinterpret_cast<const float4*>(&A[(size_t)(mBase+row)*Ee + k0 + kq]);
            As[kq+0][row] = v.x; As[kq+1][row] = v.y; As[kq+2][row] = v.z; As[kq+3][row] = v.w;
        }
        #pragma unroll
        for (int l = 0; l < 2; ++l) {
            int f4 = tid + l*256;
            int row = f4 >> 3, kq = (f4 & 7) << 2;
            float4 v = *reinterpret_cast<const float4*>(&W[(size_t)(nBase+row)*Ee + k0 + kq]);
            Bs[kq+0][row] = v.x; Bs[kq+1][row] = v.y; Bs[kq+2][row] = v.z; Bs[kq+3][row] = v.w;
        }
        __syncthreads();
        #pragma unroll
        for (int kk = 0; kk < 32; ++kk) {
            float4 a0 = *reinterpret_cast<const float4*>(&As[kk][ty*8]);
            float4 a1 = *reinterpret_cast<const float4*>(&As[kk][ty*8+4]);
            float4 b0 = *reinterpret_cast<const float4*>(&Bs[kk][tx*4]);
            float am[8] = {a0.x,a0.y,a0.z,a0.w,a1.x,a1.y,a1.z,a1.w};
            float bn[4] = {b0.x,b0.y,b0.z,b0.w};
            #pragma unroll
            for (int i = 0; i < 8; ++i)
                #pragma unroll
                for (int j = 0; j < 4; ++j) acc[i][j] = fmaf(am[i], bn[j], acc[i][j]);
        }
        __syncthreads();
    }
    #pragma unroll
    for (int i = 0; i < 8; ++i) {
        float4 v = make_float4(acc[i][0], acc[i][1], acc[i][2], acc[i][3]);
        *reinterpret_cast<float4*>(&C[(size_t)(mBase + ty*8 + i)*Ee + nBase + tx*4]) = v;
    }
}

// ---------------- generic mobius fix (fp32 out), src may equal dst ----------------
__global__ __launch_bounds__(256) void mobius_fix_kernel(const float* src, float* dst,
                                                         const float* __restrict__ xn_buf,
                                                         const float* __restrict__ bias) {
    __shared__ float red[4], red2[4];
    size_t row = blockIdx.x;
    const float* m = src + row * Ee;
    float mv[3], bv[3];
    float ss = 0.f;
    #pragma unroll
    for (int l = 0; l < 3; ++l) { mv[l] = m[threadIdx.x + l*256]; ss += mv[l]*mv[l]; }
    float mxn2 = block_sum_256(ss, red);
    float mxn = fmaxf(sqrtf(mxn2), 1e-15f);
    float xn = xn_buf[row];
    float xc = fminf(xn, 1.f - 1e-7f);
    float at = 0.5f * logf((1.f + xc) / (1.f - xc));
    float th = tanhf(mxn / xn * at);
    float scale = th / mxn;
    float m2 = th * th;
    float mb = 0.f, b2 = 0.f;
    #pragma unroll
    for (int l = 0; l < 3; ++l) {
        bv[l] = bias[threadIdx.x + l*256];
        mv[l] *= scale;
        mb += mv[l]*bv[l];
        b2 += bv[l]*bv[l];
    }
    mb = block_sum_256(mb, red);
    b2 = block_sum_256(b2, red2);
    float ncoef = 1.f + 2.f*mb + b2;
    float bcoef = 1.f - m2;
    float inv = 1.f / (1.f + 2.f*mb + m2*b2 + 1e-15f);
    float* d = dst + row * Ee;
    #pragma unroll
    for (int l = 0; l < 3; ++l)
        d[threadIdx.x + l*256] = (ncoef*mv[l] + bcoef*bv[l]) * inv;
}

// ---------------- mobius fix for K: write clamped bf16 hi/lo + per-head k2 ----------------
__global__ __launch_bounds__(256) void fix_pack_k_kernel(const float* __restrict__ src,
                                                         const float* __restrict__ xn_buf,
                                                         const float* __restrict__ bias,
                                                         unsigned short* __restrict__ Khi,
                                                         unsigned short* __restrict__ Klo,
                                                         float* __restrict__ k2g) {
    __shared__ float red[4], red2[4];
    size_t row = blockIdx.x;
    const int tid = threadIdx.x;
    const float* m = src + row * Ee;
    float mv[3], bv[3];
    float ss = 0.f;
    #pragma unroll
    for (int l = 0; l < 3; ++l) { mv[l] = m[tid + l*256]; ss += mv[l]*mv[l]; }
    float mxn2 = block_sum_256(ss, red);
    float mxn = fmaxf(sqrtf(mxn2), 1e-15f);
    float xn = xn_buf[row];
    float xc = fminf(xn, 1.f - 1e-7f);
    float at = 0.5f * logf((1.f + xc) / (1.f - xc));
    float th = tanhf(mxn / xn * at);
    float scale = th / mxn;
    float m2 = th * th;
    float mb = 0.f, b2 = 0.f;
    #pragma unroll
    for (int l = 0; l < 3; ++l) {
        bv[l] = bias[tid + l*256];
        mv[l] *= scale;
        mb += mv[l]*bv[l];
        b2 += bv[l]*bv[l];
    }
    mb = block_sum_256(mb, red);
    b2 = block_sum_256(b2, red2);
    float ncoef = 1.f + 2.f*mb + b2;
    float bcoef = 1.f - m2;
    float inv = 1.f / (1.f + 2.f*mb + m2*b2 + 1e-15f);
    const int lane = tid & 63, wv = tid >> 6;
    #pragma unroll
    for (int l = 0; l < 3; ++l) {
        float f = (ncoef*mv[l] + bcoef*bv[l]) * inv;
        float c = fminf(f, 1.f - 1e-5f);
        unsigned short hi = bf16_rne(c);
        Khi[row*Ee + tid + l*256] = hi;
        Klo[row*Ee + tid + l*256] = bf16_rne(c - bf16f(hi));
        float s2 = c*c;
        #pragma unroll
        for (int off = 1; off < 64; off <<= 1) s2 += __shfl_xor(s2, off);
        if (lane == 0) k2g[(size_t)(wv + 4*l)*Mm + row] = s2;
    }
}

// ---------------- mobius fix for Q: fp32 out (in-place) + per-head q2 (clamped) ----------------
__global__ __launch_bounds__(256) void fix_pack_q2_kernel(const float* src, float* dst,
                                                          const float* __restrict__ xn_buf,
                                                          const float* __restrict__ bias,
                                                          float* __restrict__ q2g) {
    __shared__ float red[4], red2[4];
    size_t row = blockIdx.x;
    const int tid = threadIdx.x;
    const float* m = src + row * Ee;
    float mv[3], bv[3];
    float ss = 0.f;
    #pragma unroll
    for (int l = 0; l < 3; ++l) { mv[l] = m[tid + l*256]; ss += mv[l]*mv[l]; }
    float mxn2 = block_sum_256(ss, red);
    float mxn = fmaxf(sqrtf(mxn2), 1e-15f);
    float xn = xn_buf[row];
    float xc = fminf(xn, 1.f - 1e-7f);
    float at = 0.5f * logf((1.f + xc) / (1.f - xc));
    float th = tanhf(mxn / xn * at);
    float scale = th / mxn;
    float m2 = th * th;
    float mb = 0.f, b2 = 0.f;
    #pragma unroll
    for (int l = 0; l < 3; ++l) {
        bv[l] = bias[tid + l*256];
        mv[l] *= scale;
        mb += mv[l]*bv[l];
        b2 += bv[l]*bv[l];
    }
    mb = block_sum_256(mb, red);
    b2 = block_sum_256(b2, red2);
    float ncoef = 1.f + 2.f*mb + b2;
    float bcoef = 1.f - m2;
    float inv = 1.f / (1.f + 2.f*mb + m2*b2 + 1e-15f);
    float* d = dst + row * Ee;
    const int lane = tid & 63, wv = tid >> 6;
    #pragma unroll
    for (int l = 0; l < 3; ++l) {
        float f = (ncoef*mv[l] + bcoef*bv[l]) * inv;
        d[tid + l*256] = f;
        float c = fminf(f, 1.f - 1e-5f);
        float s2 = c*c;
        #pragma unroll
        for (int off = 1; off < 64; off <<= 1) s2 += __shfl_xor(s2, off);
        if (lane == 0) q2g[(size_t)(wv + 4*l)*Mm + row] = s2;
    }
}

// ---------------- V transpose + bf16 hi/lo pack: [row][768] -> [b,h,d][1024] ----------------
__global__ __launch_bounds__(256) void transpose_pack_v_kernel(const float* __restrict__ V,
                                                               unsigned short* __restrict__ Vhi,
                                                               unsigned short* __restrict__ Vlo) {
    __shared__ float t[64][65];
    const int tid = threadIdx.x;
    const int st = blockIdx.x, h = blockIdx.y, b = blockIdx.z;
    {
        int sr = tid >> 2, d0 = (tid & 3) * 16;
        const float* vp = V + ((size_t)b*Ss + st*64 + sr)*Ee + h*64 + d0;
        #pragma unroll
        for (int u = 0; u < 4; ++u) {
            float4 v = *reinterpret_cast<const float4*>(vp + u*4);
            t[sr][d0+u*4+0] = v.x; t[sr][d0+u*4+1] = v.y;
            t[sr][d0+u*4+2] = v.z; t[sr][d0+u*4+3] = v.w;
        }
    }
    __syncthreads();
    {
        int d = tid >> 2, s0 = (tid & 3) * 16;
        unsigned hu[8], lu[8];
        #pragma unroll
        for (int i = 0; i < 8; ++i) {
            float f0 = t[s0 + 2*i][d], f1 = t[s0 + 2*i + 1][d];
            unsigned short h0 = bf16_rne(f0), h1 = bf16_rne(f1);
            hu[i] = (unsigned)h0 | ((unsigned)h1 << 16);
            lu[i] = (unsigned)bf16_rne(f0 - bf16f(h0)) | ((unsigned)bf16_rne(f1 - bf16f(h1)) << 16);
        }
        size_t obase = (((size_t)b*Hh + h)*64 + d)*Ss + st*64 + s0;
        uint4 a0 = make_uint4(hu[0],hu[1],hu[2],hu[3]);
        uint4 a1 = make_uint4(hu[4],hu[5],hu[6],hu[7]);
        uint4 c0 = make_uint4(lu[0],lu[1],lu[2],lu[3]);
        uint4 c1 = make_uint4(lu[4],lu[5],lu[6],lu[7]);
        *reinterpret_cast<uint4*>(&Vhi[obase])     = a0;
        *reinterpret_cast<uint4*>(&Vhi[obase + 8]) = a1;
        *reinterpret_cast<uint4*>(&Vlo[obase])     = c0;
        *reinterpret_cast<uint4*>(&Vlo[obase + 8]) = c1;
    }
}

// ---------------- MFMA attention: 64 q-rows/block, split-bf16, no-max softmax ----------------
// O aliases Q (block reads exactly the rows/head-cols it later writes).
__global__ __launch_bounds__(256) void attn_mfma_kernel(
    const float* Q,
    const unsigned short* __restrict__ Khi, const unsigned short* __restrict__ Klo,
    const unsigned short* __restrict__ Vhi, const unsigned short* __restrict__ Vlo,
    const float* __restrict__ q2g, const float* __restrict__ k2g,
    const float* __restrict__ hs, float* O)
{
    __shared__ alignas(16) unsigned short KHs[64][64];
    __shared__ alignas(16) unsigned short KLs[64][64];
    __shared__ alignas(16) unsigned short VHs[64][64];
    __shared__ alignas(16) unsigned short VLs[64][64];
    __shared__ alignas(16) unsigned short PHs[4][16][64];
    __shared__ alignas(16) unsigned short PLs[4][16][64];
    __shared__ float q2s[64], k2s[64];

    const int tid  = threadIdx.x;
    const int lane = tid & 63, w = tid >> 6;
    const int g = lane >> 4, lg = lane & 15;
    const int qt = blockIdx.x, h = blockIdx.y, b = blockIdx.z;
    const int q0 = qt * 64, hoff = h * 64;
    const size_t rowB = (size_t)b * Ss;

    if (tid < 64) q2s[tid] = q2g[(size_t)h*Mm + rowB + q0 + tid];

    // Q fragments (clamped, hi/lo split), kept in registers for the whole kernel.
    const float* qp = Q + (rowB + q0 + 16*w + lg)*Ee + hoff;
    s16x8 qh[2], ql[2];
    #pragma unroll
    for (int dh = 0; dh < 2; ++dh) {
        const int d0 = dh*32 + g*8;
        float4 v0 = *reinterpret_cast<const float4*>(qp + d0);
        float4 v1 = *reinterpret_cast<const float4*>(qp + d0 + 4);
        float vv[8] = {v0.x,v0.y,v0.z,v0.w,v1.x,v1.y,v1.z,v1.w};
        #pragma unroll
        for (int i = 0; i < 8; ++i) {
            float c = fminf(vv[i], 1.f - 1e-5f);
            unsigned short hi = bf16_rne(c);
            qh[dh][i] = (short)hi;
            ql[dh][i] = (short)bf16_rne(c - bf16f(hi));
        }
    }
    const float inv_s = 1.f / (hs[h] * 8.f);
    __syncthreads();
    const float q2v  = q2s[16*w + lg];
    const float omq2 = 1.f - q2v;

    f32x4 zero4 = {0.f, 0.f, 0.f, 0.f};
    f32x4 oacc[4];
    #pragma unroll
    for (int i = 0; i < 4; ++i) oacc[i] = zero4;
    float lsum = 0.f;

    for (int kt = 0; kt < 16; ++kt) {
        __syncthreads();   // previous PV reads complete
        {   // stage K/V tiles, 16B chunks, XOR-swizzled within each 128B row
            const int row = tid >> 3, row2 = row + 32;
            const int ch  = tid & 7;
            const int s1 = (ch ^ (row  & 7)) * 8;
            const int s2 = (ch ^ (row2 & 7)) * 8;
            const size_t kgo = (rowB + kt*64)*Ee + hoff + ch*8;
            *(s16x8*)&KHs[row ][s1] = *(const s16x8*)&Khi[kgo + (size_t)row *Ee];
            *(s16x8*)&KHs[row2][s2] = *(const s16x8*)&Khi[kgo + (size_t)row2*Ee];
            *(s16x8*)&KLs[row ][s1] = *(const s16x8*)&Klo[kgo + (size_t)row *Ee];
            *(s16x8*)&KLs[row2][s2] = *(const s16x8*)&Klo[kgo + (size_t)row2*Ee];
            const size_t vgo = (((size_t)b*Hh + h)*64)*Ss + kt*64 + ch*8;
            *(s16x8*)&VHs[row ][s1] = *(const s16x8*)&Vhi[vgo + (size_t)row *Ss];
            *(s16x8*)&VHs[row2][s2] = *(const s16x8*)&Vhi[vgo + (size_t)row2*Ss];
            *(s16x8*)&VLs[row ][s1] = *(const s16x8*)&Vlo[vgo + (size_t)row *Ss];
            *(s16x8*)&VLs[row2][s2] = *(const s16x8*)&Vlo[vgo + (size_t)row2*Ss];
            if (tid < 64) k2s[tid] = k2g[(size_t)h*Mm + rowB + kt*64 + tid];
        }
        __syncthreads();

        // ---- S^T tile = K · Q^T (rows = k-col, cols = q-row) ----
        f32x4 acc[4];
        #pragma unroll
        for (int i = 0; i < 4; ++i) acc[i] = zero4;
        #pragma unroll
        for (int nt = 0; nt < 4; ++nt) {
            const int krow = nt*16 + lg;
            const int sw = krow & 7;
            #pragma unroll
            for (int dh = 0; dh < 2; ++dh) {
                const int chk = ((dh*4 + g) ^ sw) * 8;
                s16x8 kh = *(const s16x8*)&KHs[krow][chk];
                s16x8 kl = *(const s16x8*)&KLs[krow][chk];
                acc[nt] = __builtin_amdgcn_mfma_f32_16x16x32_bf16(kh, qh[dh], acc[nt], 0, 0, 0);
                acc[nt] = __builtin_amdgcn_mfma_f32_16x16x32_bf16(kl, qh[dh], acc[nt], 0, 0, 0);
                acc[nt] = __builtin_amdgcn_mfma_f32_16x16x32_bf16(kh, ql[dh], acc[nt], 0, 0, 0);
            }
        }

        // ---- hyperbolic transform + unnormalized softmax weights -> P (bf16 hi/lo) ----
        #pragma unroll
        for (int nt = 0; nt < 4; ++nt) {
            const int j0 = nt*16 + g*4;
            float pr[4];
            #pragma unroll
            for (int r = 0; r < 4; ++r) {
                float s  = acc[nt][r];
                float k2 = k2s[j0 + r];
                float numer = 2.f*(q2v + k2) - 4.f*s;
                float denom = omq2*(1.f - k2) + 1e-15f;
                float t = fmaxf(numer/denom, 0.f);
                float dist = __logf(1.f + t + sqrtf(t*(t + 2.f)));   // arccosh(1+t)
                float sc = -fmaxf(dist, 1e-7f) * inv_s;
                float p = __expf(sc);
                lsum += p;
                pr[r] = p;
            }
            const int chq = ((j0 >> 3) ^ (lg & 7)) * 8 + (j0 & 7);
            unsigned short h0 = bf16_rne(pr[0]), h1 = bf16_rne(pr[1]);
            unsigned short h2 = bf16_rne(pr[2]), h3 = bf16_rne(pr[3]);
            *(unsigned*)&PHs[w][lg][chq]     = (unsigned)h0 | ((unsigned)h1 << 16);
            *(unsigned*)&PHs[w][lg][chq + 2] = (unsigned)h2 | ((unsigned)h3 << 16);
            unsigned short l0 = bf16_rne(pr[0] - bf16f(h0)), l1 = bf16_rne(pr[1] - bf16f(h1));
            unsigned short l2 = bf16_rne(pr[2] - bf16f(h2)), l3 = bf16_rne(pr[3] - bf16f(h3));
            *(unsigned*)&PLs[w][lg][chq]     = (unsigned)l0 | ((unsigned)l1 << 16);
            *(unsigned*)&PLs[w][lg][chq + 2] = (unsigned)l2 | ((unsigned)l3 << 16);
        }

        // ---- O += P · V (wave-private P, no barrier needed) ----
        #pragma unroll
        for (int jh = 0; jh < 2; ++jh) {
            const int pch = ((jh*4 + g) ^ (lg & 7)) * 8;
            s16x8 pah = *(const s16x8*)&PHs[w][lg][pch];
            s16x8 pal = *(const s16x8*)&PLs[w][lg][pch];
            #pragma unroll
            for (int nt2 = 0; nt2 < 4; ++nt2) {
                const int vrow = nt2*16 + lg;
                const int vch = ((jh*4 + g) ^ (vrow & 7)) * 8;
                s16x8 vh = *(const s16x8*)&VHs[vrow][vch];
                s16x8 vl = *(const s16x8*)&VLs[vrow][vch];
                oacc[nt2] = __builtin_amdgcn_mfma_f32_16x16x32_bf16(pah, vh, oacc[nt2], 0, 0, 0);
                oacc[nt2] = __builtin_amdgcn_mfma_f32_16x16x32_bf16(pah, vl, oacc[nt2], 0, 0, 0);
                oacc[nt2] = __builtin_amdgcn_mfma_f32_16x16x32_bf16(pal, vh, oacc[nt2], 0, 0, 0);
            }
        }
    }

    // ---- normalize and store ----
    lsum += __shfl_xor(lsum, 16);
    lsum += __shfl_xor(lsum, 32);   // every lane now has l[q = lg]
    #pragma unroll
    for (int r = 0; r < 4; ++r) {
        float lr = __shfl(lsum, g*4 + r, 64);   // l for output row g*4+r
        float li = 1.f / lr;
        #pragma unroll
        for (int nt2 = 0; nt2 < 4; ++nt2) {
            O[(rowB + q0 + 16*w + g*4 + r)*Ee + hoff + nt2*16 + lg] = oacc[nt2][r] * li;
        }
    }
}

extern "C" void kernel_launch(void* const* d_in, const int* in_sizes, int n_in,
                              void* d_out, int out_size, void* d_ws, size_t ws_size,
                              hipStream_t stream) {
    const float* x  = (const float*)d_in[0];
    const float* Wq = (const float*)d_in[1];
    const float* bq = (const float*)d_in[2];
    const float* Wk = (const float*)d_in[3];
    const float* bk = (const float*)d_in[4];
    const float* Wv = (const float*)d_in[5];
    const float* bv = (const float*)d_in[6];
    const float* Wo = (const float*)d_in[7];
    const float* bo = (const float*)d_in[8];
    const float* hs = (const float*)d_in[9];
    float* out = (float*)d_out;

    const size_t NE = (size_t)Mm * Ee;   // 6291456
    float* ws   = (float*)d_ws;
    float* xn_x = ws;                    // 8192
    float* xn_o = xn_x + Mm;             // 8192
    float* q2g  = xn_o + Mm;             // 98304
    float* k2g  = q2g + (size_t)Hh*Mm;   // 98304
    float* buf1 = k2g + (size_t)Hh*Mm;   // NE floats
    unsigned short* khi = (unsigned short*)(buf1 + NE);  // NE u16
    unsigned short* klo = khi + NE;
    unsigned short* vhi = klo + NE;
    unsigned short* vlo = vhi + NE;
    float* buf2 = (float*)khi;           // reuse khi+klo region for the final fp32 GEMM out

    dim3 gemm_grid(Mm/128, Ee/64);

    row_norm_kernel<<<Mm, 256, 0, stream>>>(x, xn_x);

    // K pipeline
    gemm_nt_kernel<<<gemm_grid, 256, 0, stream>>>(x, Wk, buf1);
    fix_pack_k_kernel<<<Mm, 256, 0, stream>>>(buf1, xn_x, bk, khi, klo, k2g);
    // V pipeline
    gemm_nt_kernel<<<gemm_grid, 256, 0, stream>>>(x, Wv, buf1);
    mobius_fix_kernel<<<Mm, 256, 0, stream>>>(buf1, buf1, xn_x, bv);
    transpose_pack_v_kernel<<<dim3(Ss/64, Hh, Bb), 256, 0, stream>>>(buf1, vhi, vlo);
    // Q pipeline
    gemm_nt_kernel<<<gemm_grid, 256, 0, stream>>>(x, Wq, buf1);
    fix_pack_q2_kernel<<<Mm, 256, 0, stream>>>(buf1, buf1, xn_x, bq, q2g);

    // attention (O aliases buf1)
    attn_mfma_kernel<<<dim3(Ss/64, Hh, Bb), 256, 0, stream>>>(
        buf1, khi, klo, vhi, vlo, q2g, k2g, hs, buf1);

    // output projection
    row_norm_kernel<<<Mm, 256, 0, stream>>>(buf1, xn_o);
    gemm_nt_kernel<<<gemm_grid, 256, 0, stream>>>(buf1, Wo, buf2);
    mobius_fix_kernel<<<Mm, 256, 0, stream>>>(buf2, out, xn_o, bo);
}

// Round 3
// 237.665 us; speedup vs baseline: 8.1957x; 3.4079x over previous
//
#include <hip/hip_runtime.h>
#include <hip/hip_bf16.h>
#include <math.h>

#define Bb 8
#define Ss 1024
#define Ee 768
#define Hh 12
#define Dd 64
#define Mm (Bb*Ss)      // 8192 rows
#define NW (Ee*Ee)      // 589824

typedef short  s16x8 __attribute__((ext_vector_type(8)));   // 8 bf16 (4 VGPRs)
typedef float  f32x4 __attribute__((ext_vector_type(4)));

__device__ __forceinline__ unsigned short f2bf(float f) {
    __hip_bfloat16 b = __float2bfloat16(f);   // RNE
    return *reinterpret_cast<unsigned short*>(&b);
}

// ---------------- block-wide sum over 256 threads ----------------
__device__ __forceinline__ float block_sum_256(float v, float* red) {
    #pragma unroll
    for (int off = 32; off > 0; off >>= 1) v += __shfl_down(v, off, 64);
    __syncthreads();
    if ((threadIdx.x & 63) == 0) red[threadIdx.x >> 6] = v;
    __syncthreads();
    return red[0] + red[1] + red[2] + red[3];
}

// ---------------- x (fp32) -> bf16 + row L2 norm ----------------
__global__ __launch_bounds__(256) void pack_x_kernel(const float* __restrict__ A,
                                                     unsigned short* __restrict__ Ab,
                                                     float* __restrict__ xn) {
    __shared__ float red[4];
    size_t row = blockIdx.x;
    const float* a = A + row * Ee;
    float ssum = 0.f;
    #pragma unroll
    for (int l = 0; l < 3; ++l) {
        float x = a[threadIdx.x + l*256];
        ssum += x*x;
        Ab[row*Ee + threadIdx.x + l*256] = f2bf(x);
    }
    float tot = block_sum_256(ssum, red);
    if (threadIdx.x == 0) xn[row] = fmaxf(sqrtf(tot), 1e-15f);
}

// ---------------- weights -> bf16 (4 matrices) ----------------
__global__ __launch_bounds__(256) void pack_w_kernel(const float* __restrict__ W0,
                                                     const float* __restrict__ W1,
                                                     const float* __restrict__ W2,
                                                     const float* __restrict__ W3,
                                                     unsigned short* __restrict__ Wb) {
    const float* src = (blockIdx.y == 0) ? W0 : (blockIdx.y == 1) ? W1
                     : (blockIdx.y == 2) ? W2 : W3;
    size_t idx = (size_t)blockIdx.x * 1024 + threadIdx.x * 4;
    float4 v = *reinterpret_cast<const float4*>(&src[idx]);
    uint2 o;
    o.x = (unsigned)f2bf(v.x) | ((unsigned)f2bf(v.y) << 16);
    o.y = (unsigned)f2bf(v.z) | ((unsigned)f2bf(v.w) << 16);
    *reinterpret_cast<uint2*>(Wb + (size_t)blockIdx.y * NW + idx) = o;
}

// ---------------- C[M,768](f32) = A[M,768](bf16) @ B[768,768](bf16)^T ----------------
// BM=64, BN=128, BK=64; 256 threads (4 waves); wave quadrant 32x64.
__global__ __launch_bounds__(256) void gemm_bf16_nt(const unsigned short* __restrict__ A,
                                                    const unsigned short* __restrict__ B,
                                                    float* __restrict__ C) {
    __shared__ alignas(16) unsigned short As[64][64];    // 8KB, chunk-XOR-swizzled
    __shared__ alignas(16) unsigned short Bs[128][64];   // 16KB
    const int tid = threadIdx.x, lane = tid & 63, w = tid >> 6;
    const int g = lane >> 4, lg = lane & 15;
    const int mBase = blockIdx.x * 64, nBase = blockIdx.y * 128;
    const int wr = w >> 1, wc = w & 1;
    f32x4 zero4 = {0.f,0.f,0.f,0.f};
    f32x4 acc[2][4];
    #pragma unroll
    for (int i = 0; i < 2; ++i)
        #pragma unroll
        for (int j = 0; j < 4; ++j) acc[i][j] = zero4;

    for (int k0 = 0; k0 < Ee; k0 += 64) {
        s16x8 av[2], bv[4];
        #pragma unroll
        for (int i = 0; i < 2; ++i) {
            int s = tid + i*256, r = s >> 3, c = s & 7;
            av[i] = *(const s16x8*)&A[(size_t)(mBase + r)*Ee + k0 + c*8];
        }
        #pragma unroll
        for (int i = 0; i < 4; ++i) {
            int s = tid + i*256, r = s >> 3, c = s & 7;
            bv[i] = *(const s16x8*)&B[(size_t)(nBase + r)*Ee + k0 + c*8];
        }
        __syncthreads();   // previous compute reads done
        #pragma unroll
        for (int i = 0; i < 2; ++i) {
            int s = tid + i*256, r = s >> 3, c = s & 7;
            *(s16x8*)&As[r][((c ^ (r & 7)))*8] = av[i];
        }
        #pragma unroll
        for (int i = 0; i < 4; ++i) {
            int s = tid + i*256, r = s >> 3, c = s & 7;
            *(s16x8*)&Bs[r][((c ^ (r & 7)))*8] = bv[i];
        }
        __syncthreads();
        #pragma unroll
        for (int kk = 0; kk < 2; ++kk) {
            s16x8 af[2], bfr[4];
            #pragma unroll
            for (int mi = 0; mi < 2; ++mi) {
                int ar = wr*32 + mi*16 + lg;
                af[mi] = *(const s16x8*)&As[ar][(((kk*4 + g) ^ (ar & 7)))*8];
            }
            #pragma unroll
            for (int ni = 0; ni < 4; ++ni) {
                int br = wc*64 + ni*16 + lg;
                bfr[ni] = *(const s16x8*)&Bs[br][(((kk*4 + g) ^ (br & 7)))*8];
            }
            #pragma unroll
            for (int mi = 0; mi < 2; ++mi)
                #pragma unroll
                for (int ni = 0; ni < 4; ++ni)
                    acc[mi][ni] = __builtin_amdgcn_mfma_f32_16x16x32_bf16(af[mi], bfr[ni], acc[mi][ni], 0, 0, 0);
        }
    }
    #pragma unroll
    for (int mi = 0; mi < 2; ++mi)
        #pragma unroll
        for (int ni = 0; ni < 4; ++ni)
            #pragma unroll
            for (int r = 0; r < 4; ++r)
                C[(size_t)(mBase + wr*32 + mi*16 + g*4 + r)*Ee + nBase + wc*64 + ni*16 + lg] = acc[mi][ni][r];
}

// ---------------- generic mobius fix (fp32 out), src may equal dst ----------------
__global__ __launch_bounds__(256) void mobius_fix_kernel(const float* src, float* dst,
                                                         const float* __restrict__ xn_buf,
                                                         const float* __restrict__ bias) {
    __shared__ float red[4], red2[4];
    size_t row = blockIdx.x;
    const float* m = src + row * Ee;
    float mv[3], bv[3];
    float ss = 0.f;
    #pragma unroll
    for (int l = 0; l < 3; ++l) { mv[l] = m[threadIdx.x + l*256]; ss += mv[l]*mv[l]; }
    float mxn2 = block_sum_256(ss, red);
    float mxn = fmaxf(sqrtf(mxn2), 1e-15f);
    float xn = xn_buf[row];
    float xc = fminf(xn, 1.f - 1e-7f);
    float at = 0.5f * logf((1.f + xc) / (1.f - xc));
    float th = tanhf(mxn / xn * at);
    float scale = th / mxn;
    float m2 = th * th;
    float mb = 0.f, b2 = 0.f;
    #pragma unroll
    for (int l = 0; l < 3; ++l) {
        bv[l] = bias[threadIdx.x + l*256];
        mv[l] *= scale;
        mb += mv[l]*bv[l];
        b2 += bv[l]*bv[l];
    }
    mb = block_sum_256(mb, red);
    b2 = block_sum_256(b2, red2);
    float ncoef = 1.f + 2.f*mb + b2;
    float bcoef = 1.f - m2;
    float inv = 1.f / (1.f + 2.f*mb + m2*b2 + 1e-15f);
    float* d = dst + row * Ee;
    #pragma unroll
    for (int l = 0; l < 3; ++l)
        d[threadIdx.x + l*256] = (ncoef*mv[l] + bcoef*bv[l]) * inv;
}

// ---------------- mobius fix for Q/K: clamped bf16 out + per-head sum of squares ----------------
__global__ __launch_bounds__(256) void fix_pack_qk_kernel(const float* __restrict__ src,
                                                          const float* __restrict__ xn_buf,
                                                          const float* __restrict__ bias,
                                                          unsigned short* __restrict__ Qb,
                                                          float* __restrict__ sumg) {
    __shared__ float red[4], red2[4];
    size_t row = blockIdx.x;
    const int tid = threadIdx.x;
    const float* m = src + row * Ee;
    float mv[3], bv[3];
    float ss = 0.f;
    #pragma unroll
    for (int l = 0; l < 3; ++l) { mv[l] = m[tid + l*256]; ss += mv[l]*mv[l]; }
    float mxn2 = block_sum_256(ss, red);
    float mxn = fmaxf(sqrtf(mxn2), 1e-15f);
    float xn = xn_buf[row];
    float xc = fminf(xn, 1.f - 1e-7f);
    float at = 0.5f * logf((1.f + xc) / (1.f - xc));
    float th = tanhf(mxn / xn * at);
    float scale = th / mxn;
    float m2 = th * th;
    float mb = 0.f, b2 = 0.f;
    #pragma unroll
    for (int l = 0; l < 3; ++l) {
        bv[l] = bias[tid + l*256];
        mv[l] *= scale;
        mb += mv[l]*bv[l];
        b2 += bv[l]*bv[l];
    }
    mb = block_sum_256(mb, red);
    b2 = block_sum_256(b2, red2);
    float ncoef = 1.f + 2.f*mb + b2;
    float bcoef = 1.f - m2;
    float inv = 1.f / (1.f + 2.f*mb + m2*b2 + 1e-15f);
    const int lane = tid & 63, wv = tid >> 6;
    #pragma unroll
    for (int l = 0; l < 3; ++l) {
        float f = (ncoef*mv[l] + bcoef*bv[l]) * inv;
        float c = fminf(f, 1.f - 1e-5f);
        Qb[row*Ee + tid + l*256] = f2bf(c);
        float s2 = c*c;
        #pragma unroll
        for (int off = 1; off < 64; off <<= 1) s2 += __shfl_xor(s2, off);
        if (lane == 0) sumg[(size_t)(wv + 4*l)*Mm + row] = s2;
    }
}

// ---------------- V transpose + bf16 pack: [row][768] -> [b,h,d][1024] ----------------
__global__ __launch_bounds__(256) void transpose_pack_v_kernel(const float* __restrict__ V,
                                                               unsigned short* __restrict__ Vb) {
    __shared__ float t[64][65];
    const int tid = threadIdx.x;
    const int st = blockIdx.x, h = blockIdx.y, b = blockIdx.z;
    {
        int sr = tid >> 2, d0 = (tid & 3) * 16;
        const float* vp = V + ((size_t)b*Ss + st*64 + sr)*Ee + h*64 + d0;
        #pragma unroll
        for (int u = 0; u < 4; ++u) {
            float4 v = *reinterpret_cast<const float4*>(vp + u*4);
            t[sr][d0+u*4+0] = v.x; t[sr][d0+u*4+1] = v.y;
            t[sr][d0+u*4+2] = v.z; t[sr][d0+u*4+3] = v.w;
        }
    }
    __syncthreads();
    {
        int d = tid >> 2, s0 = (tid & 3) * 16;
        unsigned hu[8];
        #pragma unroll
        for (int i = 0; i < 8; ++i) {
            float f0 = t[s0 + 2*i][d], f1 = t[s0 + 2*i + 1][d];
            hu[i] = (unsigned)f2bf(f0) | ((unsigned)f2bf(f1) << 16);
        }
        size_t obase = (((size_t)b*Hh + h)*64 + d)*Ss + st*64 + s0;
        *reinterpret_cast<uint4*>(&Vb[obase])     = make_uint4(hu[0],hu[1],hu[2],hu[3]);
        *reinterpret_cast<uint4*>(&Vb[obase + 8]) = make_uint4(hu[4],hu[5],hu[6],hu[7]);
    }
}

// ---------------- MFMA attention: 64 q-rows/block, single-bf16, no-max softmax ----------------
__global__ __launch_bounds__(256) void attn_mfma2(
    const unsigned short* __restrict__ Qb, const unsigned short* __restrict__ Kb,
    const unsigned short* __restrict__ Vb,
    const float* __restrict__ q2g, const float* __restrict__ k2g,
    const float* __restrict__ hs, float* __restrict__ O)
{
    __shared__ alignas(16) unsigned short KHs[64][64];
    __shared__ alignas(16) unsigned short VHs[64][64];
    __shared__ alignas(16) unsigned short PHs[4][16][64];
    __shared__ float us[64], vs[64], q2s[64];

    const int tid = threadIdx.x, lane = tid & 63, w = tid >> 6;
    const int g = lane >> 4, lg = lane & 15;
    const int qt = blockIdx.x, h = blockIdx.y, b = blockIdx.z;
    const int q0 = qt * 64, hoff = h * 64;
    const size_t rowB = (size_t)b * Ss;

    if (tid < 64) q2s[tid] = q2g[(size_t)h*Mm + rowB + q0 + tid];

    // Q fragments (bf16 global, clamped at pack time), registers for whole kernel.
    const unsigned short* qp = Qb + (rowB + q0 + 16*w + lg)*Ee + hoff;
    s16x8 qh[2];
    qh[0] = *(const s16x8*)&qp[g*8];
    qh[1] = *(const s16x8*)&qp[32 + g*8];
    const float nia = -1.f / (hs[h] * 8.f);   // exponent: p = u^(nia) = exp2(nia*log2 u)
    __syncthreads();
    const float q2v   = q2s[16*w + lg];
    const float a2    = 2.f * q2v;
    const float iomq2 = __builtin_amdgcn_rcpf(1.f - q2v);
    const size_t vBase = (((size_t)b*Hh + h)*64)*Ss;

    f32x4 zero4 = {0.f,0.f,0.f,0.f};
    f32x4 oacc[4];
    #pragma unroll
    for (int i = 0; i < 4; ++i) oacc[i] = zero4;
    float lsum = 0.f;

    for (int kt = 0; kt < 16; ++kt) {
        __syncthreads();   // previous tile reads complete
        #pragma unroll
        for (int i = 0; i < 2; ++i) {   // stage K (row-major) and V^T ([d][S]) tiles
            int s = tid + i*256, r = s >> 3, c = s & 7, cs = c ^ (r & 7);
            *(s16x8*)&KHs[r][cs*8] = *(const s16x8*)&Kb[(rowB + kt*64 + r)*Ee + hoff + c*8];
            *(s16x8*)&VHs[r][cs*8] = *(const s16x8*)&Vb[vBase + (size_t)r*Ss + kt*64 + c*8];
        }
        if (tid < 64) {
            float k2 = k2g[(size_t)h*Mm + rowB + kt*64 + tid];
            float ik = __builtin_amdgcn_rcpf(1.f - k2);
            us[tid] = ik;
            vs[tid] = 2.f * k2 * ik;
        }
        __syncthreads();

        // ---- S^T tile = K · Q^T ----
        f32x4 sacc[4];
        #pragma unroll
        for (int i = 0; i < 4; ++i) sacc[i] = zero4;
        #pragma unroll
        for (int nt = 0; nt < 4; ++nt) {
            const int krow = nt*16 + lg, sw = krow & 7;
            #pragma unroll
            for (int dh = 0; dh < 2; ++dh) {
                s16x8 kh = *(const s16x8*)&KHs[krow][((dh*4 + g) ^ sw)*8];
                sacc[nt] = __builtin_amdgcn_mfma_f32_16x16x32_bf16(kh, qh[dh], sacc[nt], 0, 0, 0);
            }
        }

        // ---- hyperbolic transform -> unnormalized P (bf16) ----
        #pragma unroll
        for (int nt = 0; nt < 4; ++nt) {
            const int j0 = nt*16 + g*4;
            float4 uq = *reinterpret_cast<const float4*>(&us[j0]);
            float4 vq = *reinterpret_cast<const float4*>(&vs[j0]);
            float uqa[4] = {uq.x, uq.y, uq.z, uq.w};
            float vqa[4] = {vq.x, vq.y, vq.z, vq.w};
            float pr[4];
            #pragma unroll
            for (int r = 0; r < 4; ++r) {
                float s  = sacc[nt][r];
                float wv_ = fmaf(-4.f, s, a2);                       // 2q2 - 4s
                float t  = fmaxf(iomq2 * fmaf(uqa[r], wv_, vqa[r]), 0.f);
                float sq = __builtin_amdgcn_sqrtf(fmaf(t, t, 2.f*t));
                float uu = t + 1.f + sq;                              // arccosh arg
                float p  = __builtin_amdgcn_exp2f(nia * __builtin_amdgcn_logf(uu));
                lsum += p;
                pr[r] = p;
            }
            const int chq = ((j0 >> 3) ^ (lg & 7))*8 + (j0 & 7);
            unsigned plo = (unsigned)f2bf(pr[0]) | ((unsigned)f2bf(pr[1]) << 16);
            unsigned phi = (unsigned)f2bf(pr[2]) | ((unsigned)f2bf(pr[3]) << 16);
            *reinterpret_cast<uint2*>(&PHs[w][lg][chq]) = make_uint2(plo, phi);
        }

        // ---- O += P · V (wave-private P) ----
        #pragma unroll
        for (int jh = 0; jh < 2; ++jh) {
            s16x8 pa = *(const s16x8*)&PHs[w][lg][((jh*4 + g) ^ (lg & 7))*8];
            #pragma unroll
            for (int nt2 = 0; nt2 < 4; ++nt2) {
                const int vrow = nt2*16 + lg;
                s16x8 vh = *(const s16x8*)&VHs[vrow][((jh*4 + g) ^ (vrow & 7))*8];
                oacc[nt2] = __builtin_amdgcn_mfma_f32_16x16x32_bf16(pa, vh, oacc[nt2], 0, 0, 0);
            }
        }
    }

    // ---- normalize and store ----
    lsum += __shfl_xor(lsum, 16);
    lsum += __shfl_xor(lsum, 32);
    #pragma unroll
    for (int r = 0; r < 4; ++r) {
        float lr = __shfl(lsum, g*4 + r, 64);
        float li = 1.f / lr;
        #pragma unroll
        for (int nt2 = 0; nt2 < 4; ++nt2)
            O[(rowB + q0 + 16*w + g*4 + r)*Ee + hoff + nt2*16 + lg] = oacc[nt2][r] * li;
    }
}

extern "C" void kernel_launch(void* const* d_in, const int* in_sizes, int n_in,
                              void* d_out, int out_size, void* d_ws, size_t ws_size,
                              hipStream_t stream) {
    const float* x  = (const float*)d_in[0];
    const float* Wq = (const float*)d_in[1];
    const float* bq = (const float*)d_in[2];
    const float* Wk = (const float*)d_in[3];
    const float* bk = (const float*)d_in[4];
    const float* Wv = (const float*)d_in[5];
    const float* bv = (const float*)d_in[6];
    const float* Wo = (const float*)d_in[7];
    const float* bo = (const float*)d_in[8];
    const float* hs = (const float*)d_in[9];
    float* out = (float*)d_out;

    const size_t NE = (size_t)Mm * Ee;
    float* ws   = (float*)d_ws;
    float* xn_x = ws;                         // Mm
    float* xn_o = xn_x + Mm;                  // Mm
    float* q2g  = xn_o + Mm;                  // Hh*Mm
    float* k2g  = q2g + (size_t)Hh*Mm;        // Hh*Mm
    float* buf1 = k2g + (size_t)Hh*Mm;        // NE f32
    unsigned short* xbf = (unsigned short*)(buf1 + NE);  // NE u16
    unsigned short* qbf = xbf + NE;
    unsigned short* kbf = qbf + NE;
    unsigned short* wbf = kbf + NE;           // 4*NW u16
    unsigned short* vbf = xbf;                // alias: x dead after V GEMM
    unsigned short* obf = kbf;                // alias: K dead after attn
    // total ~68.5 MB

    dim3 ggrid(Mm/64, Ee/128);   // (128, 6) = 768 blocks = 3/CU balanced

    pack_x_kernel<<<Mm, 256, 0, stream>>>(x, xbf, xn_x);
    pack_w_kernel<<<dim3(NW/1024, 4), 256, 0, stream>>>(Wq, Wk, Wv, Wo, wbf);

    // Q pipeline
    gemm_bf16_nt<<<ggrid, 256, 0, stream>>>(xbf, wbf + 0*(size_t)NW, buf1);
    fix_pack_qk_kernel<<<Mm, 256, 0, stream>>>(buf1, xn_x, bq, qbf, q2g);
    // K pipeline
    gemm_bf16_nt<<<ggrid, 256, 0, stream>>>(xbf, wbf + 1*(size_t)NW, buf1);
    fix_pack_qk_kernel<<<Mm, 256, 0, stream>>>(buf1, xn_x, bk, kbf, k2g);
    // V pipeline (x dead after this GEMM -> vbf may alias xbf)
    gemm_bf16_nt<<<ggrid, 256, 0, stream>>>(xbf, wbf + 2*(size_t)NW, buf1);
    mobius_fix_kernel<<<Mm, 256, 0, stream>>>(buf1, buf1, xn_x, bv);
    transpose_pack_v_kernel<<<dim3(Ss/64, Hh, Bb), 256, 0, stream>>>(buf1, vbf);

    // attention -> fp32 O in buf1
    attn_mfma2<<<dim3(Ss/64, Hh, Bb), 256, 0, stream>>>(qbf, kbf, vbf, q2g, k2g, hs, buf1);

    // output projection
    pack_x_kernel<<<Mm, 256, 0, stream>>>(buf1, obf, xn_o);
    gemm_bf16_nt<<<ggrid, 256, 0, stream>>>(obf, wbf + 3*(size_t)NW, buf1);
    mobius_fix_kernel<<<Mm, 256, 0, stream>>>(buf1, out, xn_o, bo);
}

// Round 4
// 208.975 us; speedup vs baseline: 9.3209x; 1.1373x over previous
//
#include <hip/hip_runtime.h>
#include <hip/hip_bf16.h>
#include <math.h>

#define Bb 8
#define Ss 1024
#define Ee 768
#define Hh 12
#define Dd 64
#define Mm (Bb*Ss)      // 8192 rows
#define NW (Ee*Ee)      // 589824
#define LQKV 2304       // fused QKV row stride (u16 elements)

typedef short  s16x8 __attribute__((ext_vector_type(8)));   // 8 bf16 (4 VGPRs)
typedef float  f32x4 __attribute__((ext_vector_type(4)));

__device__ __forceinline__ unsigned short f2bf(float f) {
    __hip_bfloat16 b = __float2bfloat16(f);   // RNE
    return *reinterpret_cast<unsigned short*>(&b);
}
__device__ __forceinline__ float bf2f(unsigned short h) {
    return __uint_as_float(((unsigned)h) << 16);
}

// ---------------- block-wide sum over 256 threads ----------------
__device__ __forceinline__ float block_sum_256(float v, float* red) {
    #pragma unroll
    for (int off = 32; off > 0; off >>= 1) v += __shfl_down(v, off, 64);
    __syncthreads();
    if ((threadIdx.x & 63) == 0) red[threadIdx.x >> 6] = v;
    __syncthreads();
    return red[0] + red[1] + red[2] + red[3];
}

// ---------------- x (fp32) -> bf16 + row L2 norm ----------------
__global__ __launch_bounds__(256) void pack_x_kernel(const float* __restrict__ A,
                                                     unsigned short* __restrict__ Ab,
                                                     float* __restrict__ xn) {
    __shared__ float red[4];
    size_t row = blockIdx.x;
    const float* a = A + row * Ee;
    float ssum = 0.f;
    #pragma unroll
    for (int l = 0; l < 3; ++l) {
        float x = a[threadIdx.x + l*256];
        ssum += x*x;
        Ab[row*Ee + threadIdx.x + l*256] = f2bf(x);
    }
    float tot = block_sum_256(ssum, red);
    if (threadIdx.x == 0) xn[row] = fmaxf(sqrtf(tot), 1e-15f);
}

// ---------------- per-row L2 norm over strided bf16 rows ----------------
__global__ __launch_bounds__(256) void row_norm_bf16(const unsigned short* __restrict__ A,
                                                     float* __restrict__ out) {
    __shared__ float red[4];
    size_t row = blockIdx.x;
    const unsigned short* a = A + row * LQKV;   // O lives in qkv buffer, stride 2304
    float s = 0.f;
    #pragma unroll
    for (int l = 0; l < 3; ++l) { float x = bf2f(a[threadIdx.x + l*256]); s += x*x; }
    float tot = block_sum_256(s, red);
    if (threadIdx.x == 0) out[row] = fmaxf(sqrtf(tot), 1e-15f);
}

// ---------------- weights -> bf16 (4 matrices, contiguous [3072][768]) ----------------
__global__ __launch_bounds__(256) void pack_w_kernel(const float* __restrict__ W0,
                                                     const float* __restrict__ W1,
                                                     const float* __restrict__ W2,
                                                     const float* __restrict__ W3,
                                                     unsigned short* __restrict__ Wb) {
    const float* src = (blockIdx.y == 0) ? W0 : (blockIdx.y == 1) ? W1
                     : (blockIdx.y == 2) ? W2 : W3;
    size_t idx = (size_t)blockIdx.x * 1024 + threadIdx.x * 4;
    float4 v = *reinterpret_cast<const float4*>(&src[idx]);
    uint2 o;
    o.x = (unsigned)f2bf(v.x) | ((unsigned)f2bf(v.y) << 16);
    o.y = (unsigned)f2bf(v.z) | ((unsigned)f2bf(v.w) << 16);
    *reinterpret_cast<uint2*>(Wb + (size_t)blockIdx.y * NW + idx) = o;
}

// ---------------- C[M,N] = A[M,768](bf16,lda) @ B[N,768](bf16)^T ----------------
// BM=64, BN=128, BK=64; 256 threads; OUT16: bf16 C, else fp32 C.
template<int OUT16>
__global__ __launch_bounds__(256) void gemm_bf16_nt(const unsigned short* __restrict__ A,
                                                    int lda,
                                                    const unsigned short* __restrict__ B,
                                                    void* __restrict__ Cout, int ldc) {
    __shared__ alignas(16) unsigned short As[64][64];    // 8KB, chunk-XOR-swizzled
    __shared__ alignas(16) unsigned short Bs[128][64];   // 16KB
    const int tid = threadIdx.x, lane = tid & 63, w = tid >> 6;
    const int g = lane >> 4, lg = lane & 15;
    const int mBase = blockIdx.x * 64, nBase = blockIdx.y * 128;
    const int wr = w >> 1, wc = w & 1;
    f32x4 zero4 = {0.f,0.f,0.f,0.f};
    f32x4 acc[2][4];
    #pragma unroll
    for (int i = 0; i < 2; ++i)
        #pragma unroll
        for (int j = 0; j < 4; ++j) acc[i][j] = zero4;

    for (int k0 = 0; k0 < Ee; k0 += 64) {
        s16x8 av[2], bv[4];
        #pragma unroll
        for (int i = 0; i < 2; ++i) {
            int s = tid + i*256, r = s >> 3, c = s & 7;
            av[i] = *(const s16x8*)&A[(size_t)(mBase + r)*lda + k0 + c*8];
        }
        #pragma unroll
        for (int i = 0; i < 4; ++i) {
            int s = tid + i*256, r = s >> 3, c = s & 7;
            bv[i] = *(const s16x8*)&B[(size_t)(nBase + r)*Ee + k0 + c*8];
        }
        __syncthreads();
        #pragma unroll
        for (int i = 0; i < 2; ++i) {
            int s = tid + i*256, r = s >> 3, c = s & 7;
            *(s16x8*)&As[r][((c ^ (r & 7)))*8] = av[i];
        }
        #pragma unroll
        for (int i = 0; i < 4; ++i) {
            int s = tid + i*256, r = s >> 3, c = s & 7;
            *(s16x8*)&Bs[r][((c ^ (r & 7)))*8] = bv[i];
        }
        __syncthreads();
        #pragma unroll
        for (int kk = 0; kk < 2; ++kk) {
            s16x8 af[2], bfr[4];
            #pragma unroll
            for (int mi = 0; mi < 2; ++mi) {
                int ar = wr*32 + mi*16 + lg;
                af[mi] = *(const s16x8*)&As[ar][(((kk*4 + g) ^ (ar & 7)))*8];
            }
            #pragma unroll
            for (int ni = 0; ni < 4; ++ni) {
                int br = wc*64 + ni*16 + lg;
                bfr[ni] = *(const s16x8*)&Bs[br][(((kk*4 + g) ^ (br & 7)))*8];
            }
            #pragma unroll
            for (int mi = 0; mi < 2; ++mi)
                #pragma unroll
                for (int ni = 0; ni < 4; ++ni)
                    acc[mi][ni] = __builtin_amdgcn_mfma_f32_16x16x32_bf16(af[mi], bfr[ni], acc[mi][ni], 0, 0, 0);
        }
    }
    #pragma unroll
    for (int mi = 0; mi < 2; ++mi)
        #pragma unroll
        for (int ni = 0; ni < 4; ++ni)
            #pragma unroll
            for (int r = 0; r < 4; ++r) {
                size_t off = (size_t)(mBase + wr*32 + mi*16 + g*4 + r)*ldc + nBase + wc*64 + ni*16 + lg;
                if (OUT16) ((unsigned short*)Cout)[off] = f2bf(acc[mi][ni][r]);
                else       ((float*)Cout)[off] = acc[mi][ni][r];
            }
}

// ---------------- fused mobius fix for Q/K/V, in-place bf16, + per-head sums ----------------
// grid (Mm, 3): y=0 Q (clamp+q2), y=1 K (clamp+k2), y=2 V (plain)
__global__ __launch_bounds__(256) void fix_qkv_kernel(unsigned short* __restrict__ QKV,
                                                      const float* __restrict__ xn_buf,
                                                      const float* __restrict__ bq,
                                                      const float* __restrict__ bk,
                                                      const float* __restrict__ bv_,
                                                      float* __restrict__ q2g,
                                                      float* __restrict__ k2g) {
    __shared__ float red[4], red2[4];
    const int which = blockIdx.y;
    size_t row = blockIdx.x;
    const int tid = threadIdx.x;
    const float* bias = (which == 0) ? bq : (which == 1) ? bk : bv_;
    unsigned short* m = QKV + row * LQKV + which * Ee;
    float mv[3], bv[3];
    float ss = 0.f;
    #pragma unroll
    for (int l = 0; l < 3; ++l) { mv[l] = bf2f(m[tid + l*256]); ss += mv[l]*mv[l]; }
    float mxn2 = block_sum_256(ss, red);
    float mxn = fmaxf(sqrtf(mxn2), 1e-15f);
    float xn = xn_buf[row];
    float xc = fminf(xn, 1.f - 1e-7f);
    float at = 0.5f * logf((1.f + xc) / (1.f - xc));
    float th = tanhf(mxn / xn * at);
    float scale = th / mxn;
    float m2 = th * th;
    float mb = 0.f, b2 = 0.f;
    #pragma unroll
    for (int l = 0; l < 3; ++l) {
        bv[l] = bias[tid + l*256];
        mv[l] *= scale;
        mb += mv[l]*bv[l];
        b2 += bv[l]*bv[l];
    }
    mb = block_sum_256(mb, red);
    b2 = block_sum_256(b2, red2);
    float ncoef = 1.f + 2.f*mb + b2;
    float bcoef = 1.f - m2;
    float inv = 1.f / (1.f + 2.f*mb + m2*b2 + 1e-15f);
    const int lane = tid & 63, wv = tid >> 6;
    if (which < 2) {
        float* sumg = (which == 0) ? q2g : k2g;
        #pragma unroll
        for (int l = 0; l < 3; ++l) {
            float f = (ncoef*mv[l] + bcoef*bv[l]) * inv;
            float c = fminf(f, 1.f - 1e-5f);
            m[tid + l*256] = f2bf(c);
            float s2 = c*c;
            #pragma unroll
            for (int off = 1; off < 64; off <<= 1) s2 += __shfl_xor(s2, off);
            if (lane == 0) sumg[(size_t)(wv + 4*l)*Mm + row] = s2;
        }
    } else {
        #pragma unroll
        for (int l = 0; l < 3; ++l)
            m[tid + l*256] = f2bf((ncoef*mv[l] + bcoef*bv[l]) * inv);
    }
}

// ---------------- V transpose (bf16 -> bf16): qkv v-region -> [b,h,d][1024] ----------------
__global__ __launch_bounds__(256) void transpose_v_kernel(const unsigned short* __restrict__ QKV,
                                                          unsigned short* __restrict__ Vb) {
    __shared__ unsigned short t[64][72];
    const int tid = threadIdx.x;
    const int st = blockIdx.x, h = blockIdx.y, b = blockIdx.z;
    {
        int sr = tid >> 2, d0 = (tid & 3) * 16;
        const unsigned short* vp = QKV + ((size_t)b*Ss + st*64 + sr)*LQKV + 2*Ee + h*64 + d0;
        *(s16x8*)&t[sr][d0]     = *(const s16x8*)&vp[0];
        *(s16x8*)&t[sr][d0 + 8] = *(const s16x8*)&vp[8];
    }
    __syncthreads();
    {
        int d = tid >> 2, s0 = (tid & 3) * 16;
        unsigned hu[8];
        #pragma unroll
        for (int i = 0; i < 8; ++i)
            hu[i] = (unsigned)t[s0 + 2*i][d] | ((unsigned)t[s0 + 2*i + 1][d] << 16);
        size_t obase = (((size_t)b*Hh + h)*64 + d)*Ss + st*64 + s0;
        *reinterpret_cast<uint4*>(&Vb[obase])     = make_uint4(hu[0],hu[1],hu[2],hu[3]);
        *reinterpret_cast<uint4*>(&Vb[obase + 8]) = make_uint4(hu[4],hu[5],hu[6],hu[7]);
    }
}

// ---------------- MFMA attention: 64 q-rows/block, single-bf16, no-max softmax ----------------
// Reads Q (qkv col 0..768) and K (col 768..1536); writes O bf16 over V region (col 1536..2304).
__global__ __launch_bounds__(256) void attn_mfma2(
    unsigned short* __restrict__ QKV, const unsigned short* __restrict__ Vb,
    const float* __restrict__ q2g, const float* __restrict__ k2g,
    const float* __restrict__ hs)
{
    __shared__ alignas(16) unsigned short KHs[64][64];
    __shared__ alignas(16) unsigned short VHs[64][64];
    __shared__ alignas(16) unsigned short PHs[4][16][64];
    __shared__ float us[64], vs[64];

    const int tid = threadIdx.x, lane = tid & 63, w = tid >> 6;
    const int g = lane >> 4, lg = lane & 15;
    const int qt = blockIdx.x, h = blockIdx.y, b = blockIdx.z;
    const int q0 = qt * 64, hoff = h * 64;
    const size_t rowB = (size_t)b * Ss;

    // Q fragments (bf16, clamped at fix time), registers for whole kernel.
    const unsigned short* qp = QKV + (rowB + q0 + 16*w + lg)*LQKV + hoff;
    s16x8 qh[2];
    qh[0] = *(const s16x8*)&qp[g*8];
    qh[1] = *(const s16x8*)&qp[32 + g*8];
    const float nia = -1.f / (hs[h] * 8.f);   // p = uu^nia
    const float q2v   = q2g[(size_t)h*Mm + rowB + q0 + 16*w + lg];
    const float a2    = 2.f * q2v;
    const float iomq2 = __builtin_amdgcn_rcpf(1.f - q2v);
    const size_t vBase = (((size_t)b*Hh + h)*64)*Ss;

    f32x4 zero4 = {0.f,0.f,0.f,0.f};
    f32x4 oacc[4];
    #pragma unroll
    for (int i = 0; i < 4; ++i) oacc[i] = zero4;
    float lsum = 0.f;

    for (int kt = 0; kt < 16; ++kt) {
        __syncthreads();   // previous tile reads complete
        #pragma unroll
        for (int i = 0; i < 2; ++i) {   // stage K (row-major) and V^T ([d][S]) tiles
            int s = tid + i*256, r = s >> 3, c = s & 7, cs = c ^ (r & 7);
            *(s16x8*)&KHs[r][cs*8] = *(const s16x8*)&QKV[(rowB + kt*64 + r)*LQKV + Ee + hoff + c*8];
            *(s16x8*)&VHs[r][cs*8] = *(const s16x8*)&Vb[vBase + (size_t)r*Ss + kt*64 + c*8];
        }
        if (tid < 64) {
            float k2 = k2g[(size_t)h*Mm + rowB + kt*64 + tid];
            float ik = __builtin_amdgcn_rcpf(1.f - k2);
            us[tid] = ik;
            vs[tid] = 2.f * k2 * ik;
        }
        __syncthreads();

        // ---- S^T tile = K · Q^T ----
        f32x4 sacc[4];
        #pragma unroll
        for (int i = 0; i < 4; ++i) sacc[i] = zero4;
        #pragma unroll
        for (int nt = 0; nt < 4; ++nt) {
            const int krow = nt*16 + lg, sw = krow & 7;
            #pragma unroll
            for (int dh = 0; dh < 2; ++dh) {
                s16x8 kh = *(const s16x8*)&KHs[krow][((dh*4 + g) ^ sw)*8];
                sacc[nt] = __builtin_amdgcn_mfma_f32_16x16x32_bf16(kh, qh[dh], sacc[nt], 0, 0, 0);
            }
        }

        // ---- hyperbolic transform -> unnormalized P (bf16) ----
        #pragma unroll
        for (int nt = 0; nt < 4; ++nt) {
            const int j0 = nt*16 + g*4;
            float4 uq = *reinterpret_cast<const float4*>(&us[j0]);
            float4 vq = *reinterpret_cast<const float4*>(&vs[j0]);
            float uqa[4] = {uq.x, uq.y, uq.z, uq.w};
            float vqa[4] = {vq.x, vq.y, vq.z, vq.w};
            float pr[4];
            #pragma unroll
            for (int r = 0; r < 4; ++r) {
                float s  = sacc[nt][r];
                float wv_ = fmaf(-4.f, s, a2);                       // 2q2 - 4s
                float t  = fmaxf(iomq2 * fmaf(uqa[r], wv_, vqa[r]), 0.f);
                float sq = __builtin_amdgcn_sqrtf(fmaf(t, t, 2.f*t));
                float uu = t + 1.f + sq;                              // arccosh arg
                float p  = __builtin_amdgcn_exp2f(nia * __builtin_amdgcn_logf(uu));
                lsum += p;
                pr[r] = p;
            }
            const int chq = ((j0 >> 3) ^ (lg & 7))*8 + (j0 & 7);
            unsigned plo = (unsigned)f2bf(pr[0]) | ((unsigned)f2bf(pr[1]) << 16);
            unsigned phi = (unsigned)f2bf(pr[2]) | ((unsigned)f2bf(pr[3]) << 16);
            *reinterpret_cast<uint2*>(&PHs[w][lg][chq]) = make_uint2(plo, phi);
        }

        // ---- O += P · V (wave-private P) ----
        #pragma unroll
        for (int jh = 0; jh < 2; ++jh) {
            s16x8 pa = *(const s16x8*)&PHs[w][lg][((jh*4 + g) ^ (lg & 7))*8];
            #pragma unroll
            for (int nt2 = 0; nt2 < 4; ++nt2) {
                const int vrow = nt2*16 + lg;
                s16x8 vh = *(const s16x8*)&VHs[vrow][((jh*4 + g) ^ (vrow & 7))*8];
                oacc[nt2] = __builtin_amdgcn_mfma_f32_16x16x32_bf16(pa, vh, oacc[nt2], 0, 0, 0);
            }
        }
    }

    // ---- normalize and store bf16 O over V region ----
    lsum += __shfl_xor(lsum, 16);
    lsum += __shfl_xor(lsum, 32);
    #pragma unroll
    for (int r = 0; r < 4; ++r) {
        float lr = __shfl(lsum, g*4 + r, 64);
        float li = 1.f / lr;
        #pragma unroll
        for (int nt2 = 0; nt2 < 4; ++nt2)
            QKV[(rowB + q0 + 16*w + g*4 + r)*LQKV + 2*Ee + hoff + nt2*16 + lg] = f2bf(oacc[nt2][r] * li);
    }
}

// ---------------- generic mobius fix (fp32 in/out), final projection ----------------
__global__ __launch_bounds__(256) void mobius_fix_kernel(const float* __restrict__ src, float* __restrict__ dst,
                                                         const float* __restrict__ xn_buf,
                                                         const float* __restrict__ bias) {
    __shared__ float red[4], red2[4];
    size_t row = blockIdx.x;
    const float* m = src + row * Ee;
    float mv[3], bv[3];
    float ss = 0.f;
    #pragma unroll
    for (int l = 0; l < 3; ++l) { mv[l] = m[threadIdx.x + l*256]; ss += mv[l]*mv[l]; }
    float mxn2 = block_sum_256(ss, red);
    float mxn = fmaxf(sqrtf(mxn2), 1e-15f);
    float xn = xn_buf[row];
    float xc = fminf(xn, 1.f - 1e-7f);
    float at = 0.5f * logf((1.f + xc) / (1.f - xc));
    float th = tanhf(mxn / xn * at);
    float scale = th / mxn;
    float m2 = th * th;
    float mb = 0.f, b2 = 0.f;
    #pragma unroll
    for (int l = 0; l < 3; ++l) {
        bv[l] = bias[threadIdx.x + l*256];
        mv[l] *= scale;
        mb += mv[l]*bv[l];
        b2 += bv[l]*bv[l];
    }
    mb = block_sum_256(mb, red);
    b2 = block_sum_256(b2, red2);
    float ncoef = 1.f + 2.f*mb + b2;
    float bcoef = 1.f - m2;
    float inv = 1.f / (1.f + 2.f*mb + m2*b2 + 1e-15f);
    float* d = dst + row * Ee;
    #pragma unroll
    for (int l = 0; l < 3; ++l)
        d[threadIdx.x + l*256] = (ncoef*mv[l] + bcoef*bv[l]) * inv;
}

extern "C" void kernel_launch(void* const* d_in, const int* in_sizes, int n_in,
                              void* d_out, int out_size, void* d_ws, size_t ws_size,
                              hipStream_t stream) {
    const float* x  = (const float*)d_in[0];
    const float* Wq = (const float*)d_in[1];
    const float* bq = (const float*)d_in[2];
    const float* Wk = (const float*)d_in[3];
    const float* bk = (const float*)d_in[4];
    const float* Wv = (const float*)d_in[5];
    const float* bv = (const float*)d_in[6];
    const float* Wo = (const float*)d_in[7];
    const float* bo = (const float*)d_in[8];
    const float* hs = (const float*)d_in[9];
    float* out = (float*)d_out;

    const size_t NE = (size_t)Mm * Ee;
    float* ws   = (float*)d_ws;
    float* xn_x = ws;                          // Mm
    float* xn_o = xn_x + Mm;                   // Mm
    float* q2g  = xn_o + Mm;                   // Hh*Mm
    float* k2g  = q2g + (size_t)Hh*Mm;         // Hh*Mm
    unsigned short* qkvbf = (unsigned short*)(k2g + (size_t)Hh*Mm);  // Mm*2304 u16 (37.75MB)
    unsigned short* vtbf  = qkvbf + (size_t)Mm * LQKV;               // NE u16 (12.58MB)
    unsigned short* xbf   = vtbf + NE;                               // NE u16 (12.58MB)
    unsigned short* wbf   = xbf + NE;                                // 4*NW u16 (4.72MB)
    float* fbuf = (float*)vtbf;   // fp32 [Mm][768] = exactly vtbf+xbf (both dead by then)
    // total ~68.5 MB

    pack_x_kernel<<<Mm, 256, 0, stream>>>(x, xbf, xn_x);
    pack_w_kernel<<<dim3(NW/1024, 4), 256, 0, stream>>>(Wq, Wk, Wv, Wo, wbf);

    // fused QKV projection -> bf16 [Mm][2304]
    gemm_bf16_nt<1><<<dim3(Mm/64, LQKV/128), 256, 0, stream>>>(xbf, Ee, wbf, qkvbf, LQKV);
    // mobius fix for q/k/v in place (+ per-head q2/k2)
    fix_qkv_kernel<<<dim3(Mm, 3), 256, 0, stream>>>(qkvbf, xn_x, bq, bk, bv, q2g, k2g);
    // V^T pack
    transpose_v_kernel<<<dim3(Ss/64, Hh, Bb), 256, 0, stream>>>(qkvbf, vtbf);

    // attention: O (bf16) overwrites V region of qkvbf
    attn_mfma2<<<dim3(Ss/64, Hh, Bb), 256, 0, stream>>>(qkvbf, vtbf, q2g, k2g, hs);

    // output projection
    row_norm_bf16<<<Mm, 256, 0, stream>>>(qkvbf + 2*Ee, xn_o);
    gemm_bf16_nt<0><<<dim3(Mm/64, Ee/128), 256, 0, stream>>>(qkvbf + 2*Ee, LQKV, wbf + 3*(size_t)NW, fbuf, Ee);
    mobius_fix_kernel<<<Mm, 256, 0, stream>>>(fbuf, out, xn_o, bo);
}

// Round 5
// 205.614 us; speedup vs baseline: 9.4733x; 1.0163x over previous
//
#include <hip/hip_runtime.h>
#include <hip/hip_bf16.h>
#include <math.h>

#define Bb 8
#define Ss 1024
#define Ee 768
#define Hh 12
#define Mm (Bb*Ss)      // 8192 rows
#define NW (Ee*Ee)      // 589824
#define LQKV 2304       // fused QKV row stride (u16 elements)

typedef short  s16x8 __attribute__((ext_vector_type(8)));   // 8 bf16 (4 VGPRs)
typedef float  f32x4 __attribute__((ext_vector_type(4)));

#define FENCE() __builtin_amdgcn_sched_barrier(0)
// barrier WITHOUT vmcnt drain (prefetch loads stay in flight)
#define BAR_ONLY() do { FENCE(); __builtin_amdgcn_s_barrier(); FENCE(); } while(0)
// lgkm drain (LDS writes visible) + barrier; vmcnt NOT drained
#define BAR_LGKM() do { FENCE(); asm volatile("s_waitcnt lgkmcnt(0)" ::: "memory"); FENCE(); \
                        __builtin_amdgcn_s_barrier(); FENCE(); } while(0)

__device__ __forceinline__ unsigned short f2bf(float f) {
    __hip_bfloat16 b = __float2bfloat16(f);   // RNE
    return *reinterpret_cast<unsigned short*>(&b);
}
__device__ __forceinline__ float bf2f(unsigned short h) {
    return __uint_as_float(((unsigned)h) << 16);
}

// ---------------- block-wide sum over 256 threads ----------------
__device__ __forceinline__ float block_sum_256(float v, float* red) {
    #pragma unroll
    for (int off = 32; off > 0; off >>= 1) v += __shfl_down(v, off, 64);
    __syncthreads();
    if ((threadIdx.x & 63) == 0) red[threadIdx.x >> 6] = v;
    __syncthreads();
    return red[0] + red[1] + red[2] + red[3];
}

// ---------------- fused: x->bf16 + row norm  |  weights->bf16 ----------------
__global__ __launch_bounds__(256) void pack_xw_kernel(const float* __restrict__ x,
    const float* __restrict__ W0, const float* __restrict__ W1,
    const float* __restrict__ W2, const float* __restrict__ W3,
    unsigned short* __restrict__ Xb, float* __restrict__ xn,
    unsigned short* __restrict__ Wb) {
    __shared__ float red[4];
    const int bid = blockIdx.x;
    if (bid < Mm) {
        size_t row = bid;
        const float* a = x + row * Ee;
        float ssum = 0.f;
        #pragma unroll
        for (int l = 0; l < 3; ++l) {
            float v = a[threadIdx.x + l*256];
            ssum += v*v;
            Xb[row*Ee + threadIdx.x + l*256] = f2bf(v);
        }
        float tot = block_sum_256(ssum, red);
        if (threadIdx.x == 0) xn[row] = fmaxf(sqrtf(tot), 1e-15f);
    } else {
        int idx = bid - Mm;
        const int perW = NW/1024;          // 576
        int which = idx / perW;
        int chunk = idx - which*perW;
        const float* src = (which == 0) ? W0 : (which == 1) ? W1 : (which == 2) ? W2 : W3;
        size_t off = (size_t)chunk * 1024 + threadIdx.x * 4;
        float4 v = *reinterpret_cast<const float4*>(&src[off]);
        uint2 o;
        o.x = (unsigned)f2bf(v.x) | ((unsigned)f2bf(v.y) << 16);
        o.y = (unsigned)f2bf(v.z) | ((unsigned)f2bf(v.w) << 16);
        *reinterpret_cast<uint2*>(Wb + (size_t)which * NW + off) = o;
    }
}

// ---------------- C[M,N] = A[M,768](bf16,lda) @ B[N,768](bf16)^T ----------------
// BM=64, BN=128, BK=64; 256 threads; 2-phase counted prefetch, raw barriers.
template<int OUT16>
__global__ __launch_bounds__(256) void gemm_bf16_nt(const unsigned short* __restrict__ A,
                                                    int lda,
                                                    const unsigned short* __restrict__ B,
                                                    void* __restrict__ Cout, int ldc) {
    __shared__ alignas(16) unsigned short As[64][64];    // 8KB, chunk-XOR-swizzled
    __shared__ alignas(16) unsigned short Bs[128][64];   // 16KB
    const int tid = threadIdx.x, lane = tid & 63, w = tid >> 6;
    const int g = lane >> 4, lg = lane & 15;
    const int mBase = blockIdx.x * 64, nBase = blockIdx.y * 128;
    const int wr = w >> 1, wc = w & 1;
    const int ar_ = tid >> 3, ac_ = tid & 7;
    const int csw_ = (ac_ ^ (ar_ & 7)) * 8;   // same for ar_+32/64/96 (≡ mod 8)
    f32x4 zero4 = {0.f,0.f,0.f,0.f};
    f32x4 acc[2][4];
    #pragma unroll
    for (int i = 0; i < 2; ++i)
        #pragma unroll
        for (int j = 0; j < 4; ++j) acc[i][j] = zero4;

    s16x8 av0, av1, bv0, bv1, bv2, bv3;
    #define GLOAD(k0) do { \
        av0 = *(const s16x8*)&A[(size_t)(mBase + ar_     )*lda + (k0) + ac_*8]; \
        av1 = *(const s16x8*)&A[(size_t)(mBase + ar_ + 32)*lda + (k0) + ac_*8]; \
        bv0 = *(const s16x8*)&B[(size_t)(nBase + ar_     )*Ee  + (k0) + ac_*8]; \
        bv1 = *(const s16x8*)&B[(size_t)(nBase + ar_ + 32)*Ee  + (k0) + ac_*8]; \
        bv2 = *(const s16x8*)&B[(size_t)(nBase + ar_ + 64)*Ee  + (k0) + ac_*8]; \
        bv3 = *(const s16x8*)&B[(size_t)(nBase + ar_ + 96)*Ee  + (k0) + ac_*8]; } while(0)

    GLOAD(0);
    for (int k0 = 0; k0 < Ee; k0 += 64) {
        BAR_ONLY();                        // LDS free (prev reads consumed pre-barrier)
        *(s16x8*)&As[ar_     ][csw_] = av0;
        *(s16x8*)&As[ar_ + 32][csw_] = av1;
        *(s16x8*)&Bs[ar_     ][csw_] = bv0;
        *(s16x8*)&Bs[ar_ + 32][csw_] = bv1;
        *(s16x8*)&Bs[ar_ + 64][csw_] = bv2;
        *(s16x8*)&Bs[ar_ + 96][csw_] = bv3;
        if (k0 + 64 < Ee) GLOAD(k0 + 64);  // stays in flight across the barrier
        BAR_LGKM();                        // LDS ready; vmcnt NOT drained
        __builtin_amdgcn_s_setprio(1);
        #pragma unroll
        for (int kk = 0; kk < 2; ++kk) {
            s16x8 af[2], bfr[4];
            #pragma unroll
            for (int mi = 0; mi < 2; ++mi) {
                int ar = wr*32 + mi*16 + lg;
                af[mi] = *(const s16x8*)&As[ar][(((kk*4 + g) ^ (ar & 7)))*8];
            }
            #pragma unroll
            for (int ni = 0; ni < 4; ++ni) {
                int br = wc*64 + ni*16 + lg;
                bfr[ni] = *(const s16x8*)&Bs[br][(((kk*4 + g) ^ (br & 7)))*8];
            }
            #pragma unroll
            for (int mi = 0; mi < 2; ++mi)
                #pragma unroll
                for (int ni = 0; ni < 4; ++ni)
                    acc[mi][ni] = __builtin_amdgcn_mfma_f32_16x16x32_bf16(af[mi], bfr[ni], acc[mi][ni], 0, 0, 0);
        }
        __builtin_amdgcn_s_setprio(0);
    }
    #undef GLOAD
    #pragma unroll
    for (int mi = 0; mi < 2; ++mi)
        #pragma unroll
        for (int ni = 0; ni < 4; ++ni)
            #pragma unroll
            for (int r = 0; r < 4; ++r) {
                size_t off = (size_t)(mBase + wr*32 + mi*16 + g*4 + r)*ldc + nBase + wc*64 + ni*16 + lg;
                if (OUT16) ((unsigned short*)Cout)[off] = f2bf(acc[mi][ni][r]);
                else       ((float*)Cout)[off] = acc[mi][ni][r];
            }
}

// ---------------- fused mobius fix for Q/K/V, in-place bf16, + per-head info ----------------
// grid (Mm, 3): y=0 Q (clamp + {2q2, 1/(1-q2)}), y=1 K (clamp + {ik, 2k2*ik}), y=2 V
__global__ __launch_bounds__(256) void fix_qkv_kernel(unsigned short* __restrict__ QKV,
                                                      const float* __restrict__ xn_buf,
                                                      const float* __restrict__ bq,
                                                      const float* __restrict__ bk,
                                                      const float* __restrict__ bv_,
                                                      float2* __restrict__ qinfo,
                                                      float2* __restrict__ kinfo) {
    __shared__ float red[4], red2[4];
    const int which = blockIdx.y;
    size_t row = blockIdx.x;
    const int tid = threadIdx.x;
    const float* bias = (which == 0) ? bq : (which == 1) ? bk : bv_;
    unsigned short* m = QKV + row * LQKV + which * Ee;
    float mv[3], bv[3];
    float ss = 0.f;
    #pragma unroll
    for (int l = 0; l < 3; ++l) { mv[l] = bf2f(m[tid + l*256]); ss += mv[l]*mv[l]; }
    float mxn2 = block_sum_256(ss, red);
    float mxn = fmaxf(sqrtf(mxn2), 1e-15f);
    float xn = xn_buf[row];
    float xc = fminf(xn, 1.f - 1e-7f);
    float at = 0.5f * logf((1.f + xc) / (1.f - xc));
    float th = tanhf(mxn / xn * at);
    float scale = th / mxn;
    float m2 = th * th;
    float mb = 0.f, b2 = 0.f;
    #pragma unroll
    for (int l = 0; l < 3; ++l) {
        bv[l] = bias[tid + l*256];
        mv[l] *= scale;
        mb += mv[l]*bv[l];
        b2 += bv[l]*bv[l];
    }
    mb = block_sum_256(mb, red);
    b2 = block_sum_256(b2, red2);
    float ncoef = 1.f + 2.f*mb + b2;
    float bcoef = 1.f - m2;
    float inv = 1.f / (1.f + 2.f*mb + m2*b2 + 1e-15f);
    const int lane = tid & 63, wv = tid >> 6;
    if (which < 2) {
        #pragma unroll
        for (int l = 0; l < 3; ++l) {
            float f = (ncoef*mv[l] + bcoef*bv[l]) * inv;
            float c = fminf(f, 1.f - 1e-5f);
            m[tid + l*256] = f2bf(c);
            float s2 = c*c;
            #pragma unroll
            for (int off = 1; off < 64; off <<= 1) s2 += __shfl_xor(s2, off);
            if (lane == 0) {
                if (which == 0)
                    qinfo[(size_t)(wv + 4*l)*Mm + row] = make_float2(2.f*s2, 1.f/(1.f - s2));
                else {
                    float ik = 1.f/(1.f - s2);
                    kinfo[(size_t)(wv + 4*l)*Mm + row] = make_float2(ik, 2.f*s2*ik);
                }
            }
        }
    } else {
        #pragma unroll
        for (int l = 0; l < 3; ++l)
            m[tid + l*256] = f2bf((ncoef*mv[l] + bcoef*bv[l]) * inv);
    }
}

// ---------------- V transpose (bf16 -> bf16): qkv v-region -> [b,h,d][1024] ----------------
__global__ __launch_bounds__(256) void transpose_v_kernel(const unsigned short* __restrict__ QKV,
                                                          unsigned short* __restrict__ Vb) {
    __shared__ unsigned short t[64][72];
    const int tid = threadIdx.x;
    const int st = blockIdx.x, h = blockIdx.y, b = blockIdx.z;
    {
        int sr = tid >> 2, d0 = (tid & 3) * 16;
        const unsigned short* vp = QKV + ((size_t)b*Ss + st*64 + sr)*LQKV + 2*Ee + h*64 + d0;
        *(s16x8*)&t[sr][d0]     = *(const s16x8*)&vp[0];
        *(s16x8*)&t[sr][d0 + 8] = *(const s16x8*)&vp[8];
    }
    __syncthreads();
    {
        int d = tid >> 2, s0 = (tid & 3) * 16;
        unsigned hu[8];
        #pragma unroll
        for (int i = 0; i < 8; ++i)
            hu[i] = (unsigned)t[s0 + 2*i][d] | ((unsigned)t[s0 + 2*i + 1][d] << 16);
        size_t obase = (((size_t)b*Hh + h)*64 + d)*Ss + st*64 + s0;
        *reinterpret_cast<uint4*>(&Vb[obase])     = make_uint4(hu[0],hu[1],hu[2],hu[3]);
        *reinterpret_cast<uint4*>(&Vb[obase + 8]) = make_uint4(hu[4],hu[5],hu[6],hu[7]);
    }
}

// ---------------- MFMA attention: dbuf LDS, 1 raw barrier/iter, 1-iter prefetch ----------------
// Reads Q/K from QKV, writes bf16 O over V region + per-(head,row) normalized sumsq.
__global__ __launch_bounds__(256) void attn_mfma3(
    unsigned short* __restrict__ QKV, const unsigned short* __restrict__ Vb,
    const float2* __restrict__ qinfo, const float2* __restrict__ kinfo,
    const float* __restrict__ hs, float* __restrict__ osq)
{
    __shared__ alignas(16) unsigned short KHs[2][64][64];   // 16KB
    __shared__ alignas(16) unsigned short VHs[2][64][64];   // 16KB
    __shared__ alignas(16) unsigned short PHs[4][16][64];   // 8KB
    __shared__ float us[2][64], vs[2][64];                  // 1KB

    const int tid = threadIdx.x, lane = tid & 63, w = tid >> 6;
    const int g = lane >> 4, lg = lane & 15;
    const int qt = blockIdx.x, h = blockIdx.y, b = blockIdx.z;
    const int q0 = qt * 64, hoff = h * 64;
    const size_t rowB = (size_t)b * Ss;
    const size_t hMm = (size_t)h * Mm;
    const size_t vBase = (((size_t)b*Hh + h)*64)*Ss;
    const int rr = tid >> 3, cc = tid & 7;
    const int csw = (cc ^ (rr & 7)) * 8;    // same for rr and rr+32

    const unsigned short* kgp = &QKV[(rowB + rr)*LQKV + Ee + hoff + cc*8];
    const unsigned short* vgp = &Vb[vBase + (size_t)rr*Ss + cc*8];

    // Q fragments + per-q info (registers for whole kernel)
    const unsigned short* qp = QKV + (rowB + q0 + 16*w + lg)*LQKV + hoff;
    s16x8 qh0 = *(const s16x8*)&qp[g*8];
    s16x8 qh1 = *(const s16x8*)&qp[32 + g*8];
    float2 qi = qinfo[hMm + rowB + q0 + 16*w + lg];
    const float a2 = qi.x, iomq2 = qi.y;
    const float nia = -1.f / (hs[h] * 8.f);   // p = uu^nia

    s16x8 cka, ckb, cva, cvb, nka, nkb, nva, nvb;
    #define LOADKV(ka,kb,va,vb_,kt) do { \
        ka  = *(const s16x8*)&kgp[(size_t)(kt)*64*LQKV]; \
        kb  = *(const s16x8*)&kgp[(size_t)(kt)*64*LQKV + (size_t)32*LQKV]; \
        va  = *(const s16x8*)&vgp[(kt)*64]; \
        vb_ = *(const s16x8*)&vgp[(size_t)32*Ss + (kt)*64]; } while(0)
    #define WRITEKV(bi,ka,kb,va,vb_) do { \
        *(s16x8*)&KHs[bi][rr     ][csw] = ka; \
        *(s16x8*)&KHs[bi][rr + 32][csw] = kb; \
        *(s16x8*)&VHs[bi][rr     ][csw] = va; \
        *(s16x8*)&VHs[bi][rr + 32][csw] = vb_; } while(0)

    // prologue: tiles 0,1 issued; tile0 -> buf0
    LOADKV(cka,ckb,cva,cvb, 0);
    LOADKV(nka,nkb,nva,nvb, 1);
    float2 uvC = make_float2(0.f,0.f), uvN = make_float2(0.f,0.f);
    if (tid < 64) uvC = kinfo[hMm + rowB + tid];
    if (tid < 64) uvN = kinfo[hMm + rowB + 64 + tid];
    WRITEKV(0, cka,ckb,cva,cvb);
    if (tid < 64) { us[0][tid] = uvC.x; vs[0][tid] = uvC.y; }
    BAR_LGKM();

    f32x4 zero4 = {0.f,0.f,0.f,0.f};
    f32x4 oacc[4];
    #pragma unroll
    for (int i = 0; i < 4; ++i) oacc[i] = zero4;
    float lsum = 0.f;
    int cur = 0;

    for (int kt = 0; kt < 16; ++kt) {
        // stage next tile (regs loaded >=1 iter ago) into the other buffer
        if (kt < 15) {
            WRITEKV(cur^1, nka,nkb,nva,nvb);
            if (tid < 64) { us[cur^1][tid] = uvN.x; vs[cur^1][tid] = uvN.y; }
        }
        // issue loads for tile kt+2 (covered by this iter's compute)
        if (kt < 14) {
            LOADKV(nka,nkb,nva,nvb, kt+2);
            if (tid < 64) uvN = kinfo[hMm + rowB + (kt+2)*64 + tid];
        }

        // ---- S^T tile = K · Q^T ----
        f32x4 sacc[4];
        #pragma unroll
        for (int i = 0; i < 4; ++i) sacc[i] = zero4;
        __builtin_amdgcn_s_setprio(1);
        #pragma unroll
        for (int nt = 0; nt < 4; ++nt) {
            const int krow = nt*16 + lg, sw = krow & 7;
            s16x8 kh0 = *(const s16x8*)&KHs[cur][krow][((g    ) ^ sw)*8];
            s16x8 kh1 = *(const s16x8*)&KHs[cur][krow][((4 + g) ^ sw)*8];
            sacc[nt] = __builtin_amdgcn_mfma_f32_16x16x32_bf16(kh0, qh0, sacc[nt], 0, 0, 0);
            sacc[nt] = __builtin_amdgcn_mfma_f32_16x16x32_bf16(kh1, qh1, sacc[nt], 0, 0, 0);
        }
        __builtin_amdgcn_s_setprio(0);

        // ---- hyperbolic transform -> unnormalized P (bf16 via cvt_pk) ----
        #pragma unroll
        for (int nt = 0; nt < 4; ++nt) {
            const int j0 = nt*16 + g*4;
            float4 uq = *reinterpret_cast<const float4*>(&us[cur][j0]);
            float4 vq = *reinterpret_cast<const float4*>(&vs[cur][j0]);
            float uqa[4] = {uq.x, uq.y, uq.z, uq.w};
            float vqa[4] = {vq.x, vq.y, vq.z, vq.w};
            float pr[4];
            #pragma unroll
            for (int r = 0; r < 4; ++r) {
                float s   = sacc[nt][r];
                float wv_ = fmaf(-4.f, s, a2);                        // 2q2 - 4s
                float t   = fmaxf(iomq2 * fmaf(uqa[r], wv_, vqa[r]), 0.f);
                float sq  = __builtin_amdgcn_sqrtf(fmaf(t, t, t + t));
                float uu  = t + 1.f + sq;                             // arccosh arg
                float p   = __builtin_amdgcn_exp2f(nia * __builtin_amdgcn_logf(uu));
                lsum += p;
                pr[r] = p;
            }
            unsigned p01, p23;
            asm("v_cvt_pk_bf16_f32 %0, %1, %2" : "=v"(p01) : "v"(pr[0]), "v"(pr[1]));
            asm("v_cvt_pk_bf16_f32 %0, %1, %2" : "=v"(p23) : "v"(pr[2]), "v"(pr[3]));
            const int chq = ((j0 >> 3) ^ (lg & 7))*8 + (j0 & 7);
            *reinterpret_cast<uint2*>(&PHs[w][lg][chq]) = make_uint2(p01, p23);
        }

        // ---- O += P · V (wave-private P) ----
        __builtin_amdgcn_s_setprio(1);
        #pragma unroll
        for (int jh = 0; jh < 2; ++jh) {
            s16x8 pa = *(const s16x8*)&PHs[w][lg][((jh*4 + g) ^ (lg & 7))*8];
            #pragma unroll
            for (int nt2 = 0; nt2 < 4; ++nt2) {
                const int vrow = nt2*16 + lg;
                s16x8 vh = *(const s16x8*)&VHs[cur][vrow][((jh*4 + g) ^ (vrow & 7))*8];
                oacc[nt2] = __builtin_amdgcn_mfma_f32_16x16x32_bf16(pa, vh, oacc[nt2], 0, 0, 0);
            }
        }
        __builtin_amdgcn_s_setprio(0);

        BAR_LGKM();        // single barrier per iter; vmcnt prefetch stays in flight
        cur ^= 1;
    }
    #undef LOADKV
    #undef WRITEKV

    // ---- normalize, store bf16 O, per-row sumsq ----
    lsum += __shfl_xor(lsum, 16);
    lsum += __shfl_xor(lsum, 32);
    #pragma unroll
    for (int r = 0; r < 4; ++r) {
        float lr = __shfl(lsum, g*4 + r, 64);
        float li = 1.f / lr;
        float sq = 0.f;
        #pragma unroll
        for (int nt2 = 0; nt2 < 4; ++nt2) {
            float o = oacc[nt2][r] * li;
            sq = fmaf(o, o, sq);
            QKV[(rowB + q0 + 16*w + g*4 + r)*LQKV + 2*Ee + hoff + nt2*16 + lg] = f2bf(o);
        }
        sq += __shfl_xor(sq, 1);
        sq += __shfl_xor(sq, 2);
        sq += __shfl_xor(sq, 4);
        sq += __shfl_xor(sq, 8);
        if (lg == 0) osq[hMm + rowB + q0 + 16*w + g*4 + r] = sq;
    }
}

// ---------------- final mobius fix: xn = sqrt(sum_h osq) ----------------
__global__ __launch_bounds__(256) void mobius_fix_final(const float* __restrict__ src,
                                                        float* __restrict__ dst,
                                                        const float* __restrict__ osq,
                                                        const float* __restrict__ bias) {
    __shared__ float red[4], red2[4];
    size_t row = blockIdx.x;
    const float* m = src + row * Ee;
    float mv[3], bv[3];
    float ss = 0.f;
    #pragma unroll
    for (int l = 0; l < 3; ++l) { mv[l] = m[threadIdx.x + l*256]; ss += mv[l]*mv[l]; }
    float mxn2 = block_sum_256(ss, red);
    float mxn = fmaxf(sqrtf(mxn2), 1e-15f);
    float ss2 = 0.f;
    #pragma unroll
    for (int hh = 0; hh < Hh; ++hh) ss2 += osq[(size_t)hh*Mm + row];
    float xn = fmaxf(sqrtf(ss2), 1e-15f);
    float xc = fminf(xn, 1.f - 1e-7f);
    float at = 0.5f * logf((1.f + xc) / (1.f - xc));
    float th = tanhf(mxn / xn * at);
    float scale = th / mxn;
    float m2 = th * th;
    float mb = 0.f, b2 = 0.f;
    #pragma unroll
    for (int l = 0; l < 3; ++l) {
        bv[l] = bias[threadIdx.x + l*256];
        mv[l] *= scale;
        mb += mv[l]*bv[l];
        b2 += bv[l]*bv[l];
    }
    mb = block_sum_256(mb, red);
    b2 = block_sum_256(b2, red2);
    float ncoef = 1.f + 2.f*mb + b2;
    float bcoef = 1.f - m2;
    float inv = 1.f / (1.f + 2.f*mb + m2*b2 + 1e-15f);
    float* d = dst + row * Ee;
    #pragma unroll
    for (int l = 0; l < 3; ++l)
        d[threadIdx.x + l*256] = (ncoef*mv[l] + bcoef*bv[l]) * inv;
}

extern "C" void kernel_launch(void* const* d_in, const int* in_sizes, int n_in,
                              void* d_out, int out_size, void* d_ws, size_t ws_size,
                              hipStream_t stream) {
    const float* x  = (const float*)d_in[0];
    const float* Wq = (const float*)d_in[1];
    const float* bq = (const float*)d_in[2];
    const float* Wk = (const float*)d_in[3];
    const float* bk = (const float*)d_in[4];
    const float* Wv = (const float*)d_in[5];
    const float* bv = (const float*)d_in[6];
    const float* Wo = (const float*)d_in[7];
    const float* bo = (const float*)d_in[8];
    const float* hs = (const float*)d_in[9];
    float* out = (float*)d_out;

    const size_t NE = (size_t)Mm * Ee;
    float* ws    = (float*)d_ws;
    float* xn_x  = ws;                                   // Mm f32
    float* osq   = xn_x + Mm;                            // Hh*Mm f32
    float2* qinfo = (float2*)(osq + (size_t)Hh*Mm);      // Hh*Mm f32x2
    float2* kinfo = qinfo + (size_t)Hh*Mm;               // Hh*Mm f32x2
    unsigned short* qkvbf = (unsigned short*)(kinfo + (size_t)Hh*Mm);  // Mm*2304 u16
    unsigned short* vtbf  = qkvbf + (size_t)Mm * LQKV;   // NE u16
    unsigned short* xbf   = vtbf + NE;                   // NE u16
    unsigned short* wbf   = xbf + NE;                    // 4*NW u16
    float* fbuf = (float*)vtbf;   // fp32 [Mm][768] overlays vtbf+xbf (dead by then)
    // total ~70 MB

    // pack x (bf16 + norms) and weights (bf16) in one dispatch
    pack_xw_kernel<<<Mm + 4*(NW/1024), 256, 0, stream>>>(x, Wq, Wk, Wv, Wo, xbf, xn_x, wbf);

    // fused QKV projection -> bf16 [Mm][2304]
    gemm_bf16_nt<1><<<dim3(Mm/64, LQKV/128), 256, 0, stream>>>(xbf, Ee, wbf, qkvbf, LQKV);
    // mobius fix q/k/v in place + per-head qinfo/kinfo
    fix_qkv_kernel<<<dim3(Mm, 3), 256, 0, stream>>>(qkvbf, xn_x, bq, bk, bv, qinfo, kinfo);
    // V^T pack
    transpose_v_kernel<<<dim3(Ss/64, Hh, Bb), 256, 0, stream>>>(qkvbf, vtbf);

    // attention: O (bf16) overwrites V region; osq = per-(head,row) sumsq
    attn_mfma3<<<dim3(Ss/64, Hh, Bb), 256, 0, stream>>>(qkvbf, vtbf, qinfo, kinfo, hs, osq);

    // output projection
    gemm_bf16_nt<0><<<dim3(Mm/64, Ee/128), 256, 0, stream>>>(qkvbf + 2*Ee, LQKV, wbf + 3*(size_t)NW, fbuf, Ee);
    mobius_fix_final<<<Mm, 256, 0, stream>>>(fbuf, out, osq, bo);
}